// Round 13
// baseline (1361.757 us; speedup 1.0000x reference)
//
#include <hip/hip_runtime.h>

#define N_USERS 100000
#define N_ITEMS 50000
#define N_NODES 150000
#define NNZ     2400000
#define EMB     64
#define NLAYERS 3
#define BATCH   16384
#define REG     1e-5f

#define NTILES ((N_NODES + 63) / 64)  // 2344

#define ROWS_PER_BUCKET 256
#define NB_BUCKET ((N_NODES + ROWS_PER_BUCKET - 1) / ROWS_PER_BUCKET)  // 586
#define BIN_CHUNK 4096
#define BIN_NB ((NNZ + BIN_CHUNK - 1) / BIN_CHUNK)  // 586
#define BCAP 6144   // per-bucket staging capacity: mean 4096, sigma 64

#define NCHUNK (NNZ / 16)  // 150000 (NNZ divisible by 16)

typedef __attribute__((ext_vector_type(8))) short bfrag8;  // 8 bf16 (4 VGPRs)
typedef __attribute__((ext_vector_type(4))) float vf4;     // 4 f32 acc

__device__ inline unsigned short f2bf(float x) {  // f32 -> bf16 RTN-even
    unsigned int u = __builtin_bit_cast(unsigned int, x);
    return (unsigned short)((u + 0x7fffu + ((u >> 16) & 1u)) >> 16);
}
__device__ inline float bf2f(unsigned short h) {
    unsigned int u = ((unsigned int)h) << 16;
    return __builtin_bit_cast(float, u);
}

// ---------------- init: ego_bf = bf16(concat(user_emb, item_emb)) -------
__global__ void init_ego_kernel(const float4* __restrict__ ue,
                                const float4* __restrict__ ie,
                                ushort4* __restrict__ ego_bf) {
    const int n4u = N_USERS * (EMB / 4);
    const int n4  = N_NODES * (EMB / 4);
    for (int t = blockIdx.x * blockDim.x + threadIdx.x; t < n4;
         t += gridDim.x * blockDim.x) {
        float4 v = (t < n4u) ? ue[t] : ie[t - n4u];
        ushort4 h;
        h.x = f2bf(v.x); h.y = f2bf(v.y); h.z = f2bf(v.z); h.w = f2bf(v.w);
        ego_bf[t] = h;
    }
}

// ---------------- prep: BT[layer][j][k] = bf16([W1;W2][k][j]) ------------
__global__ __launch_bounds__(256) void prep_w_kernel(
    const float* __restrict__ W1, const float* __restrict__ W2,
    unsigned short* __restrict__ BT) {
    int idx = blockIdx.x * blockDim.x + threadIdx.x;
    if (idx >= NLAYERS * 64 * 128) return;
    int l = idx / 8192;
    int rem = idx - l * 8192;
    int j = rem >> 7;        // output dim (row of BT)
    int k = rem & 127;       // concat-K
    float w = (k < 64) ? W1[l * 4096 + k * 64 + j]
                       : W2[l * 4096 + (k - 64) * 64 + j];
    BT[idx] = f2bf(w);
}

// ---------------- pass A: bucket-binned scatter (fixed-cap regions) -----
__global__ __launch_bounds__(1024) void binscatter_kernel(
    const int* __restrict__ row, const int* __restrict__ col,
    const float* __restrict__ val, int* __restrict__ bcnt,
    int2* __restrict__ stage) {
    __shared__ int hist[NB_BUCKET];
    __shared__ int wbase[NB_BUCKET];
    const int t = threadIdx.x;
    const int s = blockIdx.x * BIN_CHUNK;
    const int e = min(s + BIN_CHUNK, NNZ);

    for (int b = t; b < NB_BUCKET; b += 1024) hist[b] = 0;
    __syncthreads();
    for (int i = s + t; i < e; i += 1024)
        atomicAdd(&hist[row[i] >> 8], 1);
    __syncthreads();
    for (int b = t; b < NB_BUCKET; b += 1024) {
        int c = hist[b];
        wbase[b] = c ? atomicAdd(&bcnt[b], c) : 0;
        hist[b] = 0;  // reuse as local cursor
    }
    __syncthreads();
    for (int i = s + t; i < e; i += 1024) {
        int r = row[i];
        int b = r >> 8;
        int off = atomicAdd(&hist[b], 1);
        stage[(size_t)b * BCAP + wbase[b] + off] =
            make_int2(col[i] | ((r & 255) << 18),
                      __builtin_bit_cast(int, val[i]));
    }
}

// ---------------- bucket scan: CSR bases from measured counts -----------
__global__ __launch_bounds__(1024) void bscan_kernel(
    const int* __restrict__ bcnt, int* __restrict__ bbase) {
    __shared__ int sc[1024];
    const int t = threadIdx.x;
    int v = (t < NB_BUCKET) ? bcnt[t] : 0;
    sc[t] = v;
    __syncthreads();
    int x = v;
    for (int off = 1; off < 1024; off <<= 1) {
        int y = (t >= off) ? sc[t - off] : 0;
        __syncthreads();
        x += y;
        sc[t] = x;
        __syncthreads();
    }
    if (t < NB_BUCKET) bbase[t] = x - v;  // exclusive
    if (t == 0) bbase[NB_BUCKET] = NNZ;
}

// ---------------- pass B: row-count + scan + CSR placement (+srow) ------
__global__ __launch_bounds__(1024) void bucket_place_kernel(
    const int2* __restrict__ stage, const int* __restrict__ bcnt,
    const int* __restrict__ bbase, int* __restrict__ rp,
    int2* __restrict__ sce, int* __restrict__ srow) {
    __shared__ int cnt[ROWS_PER_BUCKET];
    __shared__ int sc[ROWS_PER_BUCKET];
    __shared__ int cur[ROWS_PER_BUCKET];
    const int b = blockIdx.x;
    const int t = threadIdx.x;
    const int row0 = b * ROWS_PER_BUCKET;
    const size_t S0 = (size_t)b * BCAP;
    const int ne = bcnt[b];
    const int B0 = bbase[b];
    if (t < 256) cnt[t] = 0;
    __syncthreads();
    for (int i = t; i < ne; i += 1024)
        atomicAdd(&cnt[(stage[S0 + i].x >> 18) & 255], 1);
    __syncthreads();
    int v = 0, x = 0;
    if (t < 256) { v = cnt[t]; x = v; sc[t] = v; }
    __syncthreads();
    for (int off = 1; off < 256; off <<= 1) {
        int y = (t < 256 && t >= off) ? sc[t - off] : 0;
        __syncthreads();
        if (t < 256) { x += y; sc[t] = x; }
        __syncthreads();
    }
    if (t < 256) {
        int excl = x - v;
        int row = row0 + t;
        if (row <= N_NODES) rp[row] = B0 + excl;  // row==N_NODES -> NNZ
        cur[t] = B0 + excl;
    }
    __syncthreads();
    for (int i = t; i < ne; i += 1024) {
        int2 pk = stage[S0 + i];
        int rl = (pk.x >> 18) & 255;
        int pos = atomicAdd(&cur[rl], 1);
        sce[pos] = make_int2(pk.x & 0x3FFFF, pk.y);
        srow[pos] = row0 + rl;
    }
}

// ---------------- SpMM: edge-parallel, persistent waves, seg-reduce -----
// Wave takes 16-edge chunks grid-stride from the row-sorted stream.
// Halves handle alternate edges (2 edges / gather instruction); runs of
// equal rows combine in registers; segment flush = 2x f32 atomicAdd.
__global__ __launch_bounds__(256) void spmm_edge_kernel(
    const int2* __restrict__ sce, const int* __restrict__ srow,
    const unsigned short* __restrict__ ego_bf, float* __restrict__ side) {
    const int lane = threadIdx.x & 63;
    const int half = lane >> 5;   // which edge of each pair
    const int sl   = lane & 31;   // dim-pair index (dims 2sl, 2sl+1)
    const unsigned* egoU = (const unsigned*)ego_bf;  // row stride 32 uints
    int wave = (blockIdx.x * blockDim.x + threadIdx.x) >> 6;
    const int nw = (gridDim.x * blockDim.x) >> 6;
    for (int ch = wave; ch < NCHUNK; ch += nw) {
        const int base = ch * 16;
        int2 c0 = sce[base + 0 + half];
        int2 c1 = sce[base + 2 + half];
        int2 c2 = sce[base + 4 + half];
        int2 c3 = sce[base + 6 + half];
        int2 c4 = sce[base + 8 + half];
        int2 c5 = sce[base + 10 + half];
        int2 c6 = sce[base + 12 + half];
        int2 c7 = sce[base + 14 + half];
        int r0 = srow[base + 0 + half];
        int r1 = srow[base + 2 + half];
        int r2 = srow[base + 4 + half];
        int r3 = srow[base + 6 + half];
        int r4 = srow[base + 8 + half];
        int r5 = srow[base + 10 + half];
        int r6 = srow[base + 12 + half];
        int r7 = srow[base + 14 + half];
        unsigned g0 = egoU[(size_t)c0.x * 32 + sl];
        unsigned g1 = egoU[(size_t)c1.x * 32 + sl];
        unsigned g2 = egoU[(size_t)c2.x * 32 + sl];
        unsigned g3 = egoU[(size_t)c3.x * 32 + sl];
        unsigned g4 = egoU[(size_t)c4.x * 32 + sl];
        unsigned g5 = egoU[(size_t)c5.x * 32 + sl];
        unsigned g6 = egoU[(size_t)c6.x * 32 + sl];
        unsigned g7 = egoU[(size_t)c7.x * 32 + sl];

        float aL, aH;
        int cur = r0;
        {
            float w = __builtin_bit_cast(float, c0.y);
            aL = w * bf2f((unsigned short)(g0 & 0xffffu));
            aH = w * bf2f((unsigned short)(g0 >> 16));
        }
#define SEG_STEP(i)                                                          \
        {                                                                    \
            float w = __builtin_bit_cast(float, c##i.y);                     \
            float xL = bf2f((unsigned short)(g##i & 0xffffu));               \
            float xH = bf2f((unsigned short)(g##i >> 16));                   \
            if (r##i == cur) {                                               \
                aL = fmaf(w, xL, aL);                                        \
                aH = fmaf(w, xH, aH);                                        \
            } else {                                                         \
                atomicAdd(&side[(size_t)cur * 64 + 2 * sl], aL);             \
                atomicAdd(&side[(size_t)cur * 64 + 2 * sl + 1], aH);         \
                cur = r##i;                                                  \
                aL = w * xL;                                                 \
                aH = w * xH;                                                 \
            }                                                                \
        }
        SEG_STEP(1) SEG_STEP(2) SEG_STEP(3) SEG_STEP(4)
        SEG_STEP(5) SEG_STEP(6) SEG_STEP(7)
#undef SEG_STEP
        atomicAdd(&side[(size_t)cur * 64 + 2 * sl], aL);
        atomicAdd(&side[(size_t)cur * 64 + 2 * sl + 1], aH);
    }
}

// ---------------- dense via MFMA bf16; f32 side in, re-zeroed -----------
__global__ __launch_bounds__(256) void gemm_dense_kernel(
    unsigned short* __restrict__ ego,            // bf16 in/out
    float* __restrict__ side,                    // f32 in, zeroed after read
    const unsigned short* __restrict__ BT, const float* __restrict__ b1,
    const float* __restrict__ b2, float* __restrict__ nrm) {
    __shared__ unsigned short A_lds[64][136];  // 272B row stride, 16B aligned
    const int tid  = threadIdx.x;
    const int lane = tid & 63, wm = tid >> 6;
    const int m = lane & 15, g = lane >> 4;
    const int base = blockIdx.x * 64;

    bfrag8 b[4][4];
#pragma unroll
    for (int nt = 0; nt < 4; ++nt)
#pragma unroll
        for (int kt = 0; kt < 4; ++kt)
            b[nt][kt] =
                *(const bfrag8*)(BT + (nt * 16 + m) * 128 + kt * 32 + g * 8);

    float bias[4];
#pragma unroll
    for (int nt = 0; nt < 4; ++nt)
        bias[nt] = b1[nt * 16 + m] + b2[nt * 16 + m];

    // stage A tile: sli = ego+side, pr = ego*side; zero side after read
#pragma unroll
    for (int it = 0; it < 2; ++it) {
        int idx = it * 256 + tid;       // 0..511
        int n = idx >> 3, c = idx & 7;  // row, 8-dim chunk
        int node = base + n;
        uint4 ev = make_uint4(0, 0, 0, 0);
        float4 s0 = make_float4(0.f, 0.f, 0.f, 0.f), s1 = s0;
        if (node < N_NODES) {
            ev = ((const uint4*)ego)[(size_t)node * 8 + c];
            s0 = ((const float4*)side)[(size_t)node * 16 + c * 2];
            s1 = ((const float4*)side)[(size_t)node * 16 + c * 2 + 1];
            float4 z = make_float4(0.f, 0.f, 0.f, 0.f);
            ((float4*)side)[(size_t)node * 16 + c * 2]     = z;
            ((float4*)side)[(size_t)node * 16 + c * 2 + 1] = z;
        }
        unsigned evu[4] = {ev.x, ev.y, ev.z, ev.w};
        float sv[8] = {s0.x, s0.y, s0.z, s0.w, s1.x, s1.y, s1.z, s1.w};
        unsigned q[4], pq[4];
#pragma unroll
        for (int j = 0; j < 4; ++j) {
            float e0 = bf2f((unsigned short)(evu[j] & 0xffffu));
            float e1 = bf2f((unsigned short)(evu[j] >> 16));
            q[j]  = f2bf(e0 + sv[2 * j]) |
                    ((unsigned)f2bf(e1 + sv[2 * j + 1]) << 16);
            pq[j] = f2bf(e0 * sv[2 * j]) |
                    ((unsigned)f2bf(e1 * sv[2 * j + 1]) << 16);
        }
        *(uint4*)&A_lds[n][c * 8]      = make_uint4(q[0], q[1], q[2], q[3]);
        *(uint4*)&A_lds[n][64 + c * 8] = make_uint4(pq[0], pq[1], pq[2], pq[3]);
    }
    __syncthreads();

    bfrag8 a[4];
#pragma unroll
    for (int kt = 0; kt < 4; ++kt)
        a[kt] = *(const bfrag8*)&A_lds[wm * 16 + m][kt * 32 + g * 8];

    vf4 acc[4];
#pragma unroll
    for (int nt = 0; nt < 4; ++nt) acc[nt] = (vf4){0.f, 0.f, 0.f, 0.f};
#pragma unroll
    for (int kt = 0; kt < 4; ++kt)
#pragma unroll
        for (int nt = 0; nt < 4; ++nt)
            acc[nt] = __builtin_amdgcn_mfma_f32_16x16x32_bf16(
                a[kt], b[nt][kt], acc[nt], 0, 0, 0);

    float o[4][4];
    float sq[4] = {0.f, 0.f, 0.f, 0.f};
#pragma unroll
    for (int nt = 0; nt < 4; ++nt)
#pragma unroll
        for (int r = 0; r < 4; ++r) {
            float v = acc[nt][r] + bias[nt];
            v = (v >= 0.f) ? v : 0.01f * v;
            o[nt][r] = v;
            sq[r] += v * v;
        }
#pragma unroll
    for (int r = 0; r < 4; ++r)
#pragma unroll
        for (int off = 1; off < 16; off <<= 1)
            sq[r] += __shfl_xor(sq[r], off, 64);  // reduce over m (same rows)

#pragma unroll
    for (int r = 0; r < 4; ++r) {
        int row = base + wm * 16 + g * 4 + r;  // C/D: row=(lane>>4)*4+reg
        if (row < N_NODES) {
#pragma unroll
            for (int nt = 0; nt < 4; ++nt)
                ego[(size_t)row * 64 + nt * 16 + m] = f2bf(o[nt][r]);
            if (m == 0) nrm[row] = fmaxf(sqrtf(sq[r]), 1e-12f);
        }
    }
}

// ---------------- batch accumulation over one 64-dim concat segment ------
__global__ __launch_bounds__(256) void batch_kernel(
    const unsigned short* __restrict__ ego_bf, const float* __restrict__ nrm,
    int use_nrm, const int* __restrict__ u, const int* __restrict__ pi,
    const int* __restrict__ ni, float* __restrict__ dot_ui,
    float* __restrict__ dot_uj, float* __restrict__ l2b) {
    const int lane = threadIdx.x & 63;
    int b = (blockIdx.x * blockDim.x + threadIdx.x) >> 6;
    if (b >= BATCH) return;
    int un = u[b];
    int pn = N_USERS + pi[b];
    int nn = N_USERS + ni[b];
    float fu = bf2f(ego_bf[(size_t)un * EMB + lane]);
    float fp = bf2f(ego_bf[(size_t)pn * EMB + lane]);
    float fn_ = bf2f(ego_bf[(size_t)nn * EMB + lane]);
    if (use_nrm) {
        fu /= nrm[un];
        fp /= nrm[pn];
        fn_ /= nrm[nn];
    }
    float dup = fu * fp;
    float dun = fu * fn_;
    float l2  = fu * fu + fp * fp + fn_ * fn_;
#pragma unroll
    for (int off = 32; off; off >>= 1) {
        dup += __shfl_xor(dup, off, 64);
        dun += __shfl_xor(dun, off, 64);
        l2  += __shfl_xor(l2, off, 64);
    }
    if (lane == 0) {
        dot_ui[b] += dup;
        dot_uj[b] += dun;
        l2b[b]    += l2;
    }
}

// ---------------- final scalar reduce ----------------
__global__ __launch_bounds__(256) void final_kernel(
    const float* __restrict__ dot_ui, const float* __restrict__ dot_uj,
    const float* __restrict__ l2b, float* __restrict__ out) {
    __shared__ float sl[256], s2[256];
    float accL = 0.f, acc2 = 0.f;
    for (int b = threadIdx.x; b < BATCH; b += 256) {
        float x = dot_ui[b] - dot_uj[b];
        float sp = (x > 0.f) ? log1pf(expf(-x)) : (-x + log1pf(expf(x)));
        accL += sp;
        acc2 += l2b[b];
    }
    sl[threadIdx.x] = accL;
    s2[threadIdx.x] = acc2;
    __syncthreads();
    for (int off = 128; off; off >>= 1) {
        if (threadIdx.x < off) {
            sl[threadIdx.x] += sl[threadIdx.x + off];
            s2[threadIdx.x] += s2[threadIdx.x + off];
        }
        __syncthreads();
    }
    if (threadIdx.x == 0)
        out[0] = sl[0] / (float)BATCH + REG * (s2[0] * 0.5f / (float)BATCH);
}

extern "C" void kernel_launch(void* const* d_in, const int* in_sizes, int n_in,
                              void* d_out, int out_size, void* d_ws,
                              size_t ws_size, hipStream_t stream) {
    const int*   adj_row  = (const int*)d_in[0];
    const int*   adj_col  = (const int*)d_in[1];
    const float* adj_val  = (const float*)d_in[2];
    const float* user_emb = (const float*)d_in[3];
    const float* item_emb = (const float*)d_in[4];
    const float* W1       = (const float*)d_in[5];
    const float* b1       = (const float*)d_in[6];
    const float* W2       = (const float*)d_in[7];
    const float* b2       = (const float*)d_in[8];
    const int*   u        = (const int*)d_in[9];
    const int*   ii       = (const int*)d_in[10];
    const int*   jj       = (const int*)d_in[11];

    char* p = (char*)d_ws;
    auto alloc = [&](size_t bytes) {
        char* q = p;
        p += (bytes + 255) & ~(size_t)255;
        return q;
    };
    unsigned short* ego    = (unsigned short*)alloc((size_t)N_NODES * EMB * 2);
    float*          side   = (float*)alloc((size_t)N_NODES * EMB * 4);
    int2*           sce    = (int2*)alloc((size_t)NNZ * 8);
    int*            srow   = (int*)alloc((size_t)NNZ * 4);
    int2*           stage  = (int2*)alloc((size_t)NB_BUCKET * BCAP * 8);
    int*            rp     = (int*)alloc((size_t)(N_NODES + 1) * 4);
    int*            bcnt   = (int*)alloc((size_t)NB_BUCKET * 4);
    int*            bbase  = (int*)alloc((size_t)(NB_BUCKET + 1) * 4);
    float*          nrm    = (float*)alloc((size_t)N_NODES * 4);
    float*          dot_ui = (float*)alloc((size_t)BATCH * 4);
    float*          dot_uj = (float*)alloc((size_t)BATCH * 4);
    float*          l2b    = (float*)alloc((size_t)BATCH * 4);
    unsigned short* BT     = (unsigned short*)alloc((size_t)NLAYERS * 8192 * 2);

    hipMemsetAsync(dot_ui, 0, BATCH * sizeof(float), stream);
    hipMemsetAsync(dot_uj, 0, BATCH * sizeof(float), stream);
    hipMemsetAsync(l2b, 0, BATCH * sizeof(float), stream);
    hipMemsetAsync(bcnt, 0, NB_BUCKET * sizeof(int), stream);
    hipMemsetAsync(side, 0, (size_t)N_NODES * EMB * sizeof(float), stream);

    prep_w_kernel<<<(NLAYERS * 8192 + 255) / 256, 256, 0, stream>>>(W1, W2, BT);

    // ---- build CSR (once; shared by all 3 layers) ----
    binscatter_kernel<<<BIN_NB, 1024, 0, stream>>>(adj_row, adj_col, adj_val,
                                                   bcnt, stage);
    bscan_kernel<<<1, 1024, 0, stream>>>(bcnt, bbase);
    bucket_place_kernel<<<NB_BUCKET, 1024, 0, stream>>>(stage, bcnt, bbase, rp,
                                                        sce, srow);

    init_ego_kernel<<<2048, 256, 0, stream>>>((const float4*)user_emb,
                                              (const float4*)item_emb,
                                              (ushort4*)ego);

    batch_kernel<<<BATCH / 4, 256, 0, stream>>>(ego, nrm, 0, u, ii, jj,
                                                dot_ui, dot_uj, l2b);

    for (int k = 0; k < NLAYERS; ++k) {
        spmm_edge_kernel<<<2048, 256, 0, stream>>>(sce, srow, ego, side);
        gemm_dense_kernel<<<NTILES, 256, 0, stream>>>(
            ego, side, BT + (size_t)k * 8192, b1 + (size_t)k * EMB,
            b2 + (size_t)k * EMB, nrm);
        batch_kernel<<<BATCH / 4, 256, 0, stream>>>(ego, nrm, 1, u, ii, jj,
                                                    dot_ui, dot_uj, l2b);
    }

    final_kernel<<<1, 256, 0, stream>>>(dot_ui, dot_uj, l2b, (float*)d_out);
}

// Round 14
// 431.949 us; speedup vs baseline: 3.1526x; 3.1526x over previous
//
#include <hip/hip_runtime.h>

#define N_USERS 100000
#define N_ITEMS 50000
#define N_NODES 150000
#define NNZ     2400000
#define EMB     64
#define NLAYERS 3
#define BATCH   16384
#define REG     1e-5f

#define NTILES ((N_NODES + 63) / 64)  // 2344

#define ROWS_PER_BUCKET 256
#define NB_BUCKET ((N_NODES + ROWS_PER_BUCKET - 1) / ROWS_PER_BUCKET)  // 586
#define BIN_CHUNK 4096
#define BIN_NB ((NNZ + BIN_CHUNK - 1) / BIN_CHUNK)  // 586
#define BCAP 6144   // per-bucket staging capacity: mean 4096, sigma 64

typedef __attribute__((ext_vector_type(8))) short bfrag8;  // 8 bf16 (4 VGPRs)
typedef __attribute__((ext_vector_type(4))) float vf4;     // 4 f32 acc

__device__ inline unsigned short f2bf(float x) {  // f32 -> bf16 RTN-even
    unsigned int u = __builtin_bit_cast(unsigned int, x);
    return (unsigned short)((u + 0x7fffu + ((u >> 16) & 1u)) >> 16);
}
__device__ inline float bf2f(unsigned short h) {
    unsigned int u = ((unsigned int)h) << 16;
    return __builtin_bit_cast(float, u);
}

// ---------------- init: ego_bf = bf16(concat(user_emb, item_emb)) -------
__global__ void init_ego_kernel(const float4* __restrict__ ue,
                                const float4* __restrict__ ie,
                                ushort4* __restrict__ ego_bf) {
    const int n4u = N_USERS * (EMB / 4);
    const int n4  = N_NODES * (EMB / 4);
    for (int t = blockIdx.x * blockDim.x + threadIdx.x; t < n4;
         t += gridDim.x * blockDim.x) {
        float4 v = (t < n4u) ? ue[t] : ie[t - n4u];
        ushort4 h;
        h.x = f2bf(v.x); h.y = f2bf(v.y); h.z = f2bf(v.z); h.w = f2bf(v.w);
        ego_bf[t] = h;
    }
}

// ---------------- prep: BT[layer][j][k] = bf16([W1;W2][k][j]) ------------
__global__ __launch_bounds__(256) void prep_w_kernel(
    const float* __restrict__ W1, const float* __restrict__ W2,
    unsigned short* __restrict__ BT) {
    int idx = blockIdx.x * blockDim.x + threadIdx.x;
    if (idx >= NLAYERS * 64 * 128) return;
    int l = idx / 8192;
    int rem = idx - l * 8192;
    int j = rem >> 7;        // output dim (row of BT)
    int k = rem & 127;       // concat-K
    float w = (k < 64) ? W1[l * 4096 + k * 64 + j]
                       : W2[l * 4096 + (k - 64) * 64 + j];
    BT[idx] = f2bf(w);
}

// ---------------- pass A: bucket-binned scatter (fixed-cap regions) -----
__global__ __launch_bounds__(1024) void binscatter_kernel(
    const int* __restrict__ row, const int* __restrict__ col,
    const float* __restrict__ val, int* __restrict__ bcnt,
    int2* __restrict__ stage) {
    __shared__ int hist[NB_BUCKET];
    __shared__ int wbase[NB_BUCKET];
    const int t = threadIdx.x;
    const int s = blockIdx.x * BIN_CHUNK;
    const int e = min(s + BIN_CHUNK, NNZ);

    for (int b = t; b < NB_BUCKET; b += 1024) hist[b] = 0;
    __syncthreads();
    for (int i = s + t; i < e; i += 1024)
        atomicAdd(&hist[row[i] >> 8], 1);
    __syncthreads();
    for (int b = t; b < NB_BUCKET; b += 1024) {
        int c = hist[b];
        wbase[b] = c ? atomicAdd(&bcnt[b], c) : 0;
        hist[b] = 0;  // reuse as local cursor
    }
    __syncthreads();
    for (int i = s + t; i < e; i += 1024) {
        int r = row[i];
        int b = r >> 8;
        int off = atomicAdd(&hist[b], 1);
        stage[(size_t)b * BCAP + wbase[b] + off] =
            make_int2(col[i] | ((r & 255) << 18),
                      __builtin_bit_cast(int, val[i]));
    }
}

// ---------------- bucket scan: CSR bases from measured counts -----------
__global__ __launch_bounds__(1024) void bscan_kernel(
    const int* __restrict__ bcnt, int* __restrict__ bbase) {
    __shared__ int sc[1024];
    const int t = threadIdx.x;
    int v = (t < NB_BUCKET) ? bcnt[t] : 0;
    sc[t] = v;
    __syncthreads();
    int x = v;
    for (int off = 1; off < 1024; off <<= 1) {
        int y = (t >= off) ? sc[t - off] : 0;
        __syncthreads();
        x += y;
        sc[t] = x;
        __syncthreads();
    }
    if (t < NB_BUCKET) bbase[t] = x - v;  // exclusive
    if (t == 0) bbase[NB_BUCKET] = NNZ;
}

// ---------------- pass B: row-count + scan + CSR placement --------------
__global__ __launch_bounds__(1024) void bucket_place_kernel(
    const int2* __restrict__ stage, const int* __restrict__ bcnt,
    const int* __restrict__ bbase, int* __restrict__ rp,
    int2* __restrict__ sce) {
    __shared__ int cnt[ROWS_PER_BUCKET];
    __shared__ int sc[ROWS_PER_BUCKET];
    __shared__ int cur[ROWS_PER_BUCKET];
    const int b = blockIdx.x;
    const int t = threadIdx.x;
    const int row0 = b * ROWS_PER_BUCKET;
    const size_t S0 = (size_t)b * BCAP;
    const int ne = bcnt[b];
    const int B0 = bbase[b];
    if (t < 256) cnt[t] = 0;
    __syncthreads();
    for (int i = t; i < ne; i += 1024)
        atomicAdd(&cnt[(stage[S0 + i].x >> 18) & 255], 1);
    __syncthreads();
    int v = 0, x = 0;
    if (t < 256) { v = cnt[t]; x = v; sc[t] = v; }
    __syncthreads();
    for (int off = 1; off < 256; off <<= 1) {
        int y = (t < 256 && t >= off) ? sc[t - off] : 0;
        __syncthreads();
        if (t < 256) { x += y; sc[t] = x; }
        __syncthreads();
    }
    if (t < 256) {
        int excl = x - v;
        int row = row0 + t;
        if (row <= N_NODES) rp[row] = B0 + excl;  // row==N_NODES -> NNZ
        cur[t] = B0 + excl;
    }
    __syncthreads();
    for (int i = t; i < ne; i += 1024) {
        int2 pk = stage[S0 + i];
        int rl = (pk.x >> 18) & 255;
        int pos = atomicAdd(&cur[rl], 1);
        sce[pos] = make_int2(pk.x & 0x3FFFF, pk.y);
    }
}

// ---------------- CSR SpMM: quarter-wave per edge, 4 dims/lane ----------
// One wave per row. Quarter q (16 lanes) reads edge (k+q)'s ego row as
// uint2 (16 x 8B = 128B) => one gather instruction covers 4 edges.
// A 16-edge iteration issues 4 gathers + 4 sce broadcasts (was 8+8).
// Reduce across quarters via shfl_xor(32)+shfl_xor(16); lanes 0-15 store.
__global__ __launch_bounds__(256) void spmm_csr_kernel(
    const int* __restrict__ rp, const int2* __restrict__ sce,
    const unsigned short* __restrict__ ego_bf,
    unsigned short* __restrict__ side_bf) {
    const int lane = threadIdx.x & 63;
    const int q    = lane >> 4;   // which edge of the 4-group
    const int ql   = lane & 15;   // dim-quad index (dims 4ql..4ql+3)
    int r = (blockIdx.x * blockDim.x + threadIdx.x) >> 6;
    if (r >= N_NODES) return;
    const uint2* egoV = (const uint2*)ego_bf;  // row stride 16 uint2
    int s = rp[r], e = rp[r + 1];
    float a0 = 0.f, a1 = 0.f, a2 = 0.f, a3 = 0.f;
    int k = s;
    for (; k + 15 < e; k += 16) {
        int2 c0 = sce[k + q];
        int2 c1 = sce[k + 4 + q];
        int2 c2 = sce[k + 8 + q];
        int2 c3 = sce[k + 12 + q];
        uint2 g0 = egoV[(size_t)c0.x * 16 + ql];
        uint2 g1 = egoV[(size_t)c1.x * 16 + ql];
        uint2 g2 = egoV[(size_t)c2.x * 16 + ql];
        uint2 g3 = egoV[(size_t)c3.x * 16 + ql];
        float w0 = __builtin_bit_cast(float, c0.y);
        float w1 = __builtin_bit_cast(float, c1.y);
        float w2 = __builtin_bit_cast(float, c2.y);
        float w3 = __builtin_bit_cast(float, c3.y);
        a0 = fmaf(w0, bf2f((unsigned short)(g0.x & 0xffffu)), a0);
        a1 = fmaf(w0, bf2f((unsigned short)(g0.x >> 16)), a1);
        a2 = fmaf(w0, bf2f((unsigned short)(g0.y & 0xffffu)), a2);
        a3 = fmaf(w0, bf2f((unsigned short)(g0.y >> 16)), a3);
        a0 = fmaf(w1, bf2f((unsigned short)(g1.x & 0xffffu)), a0);
        a1 = fmaf(w1, bf2f((unsigned short)(g1.x >> 16)), a1);
        a2 = fmaf(w1, bf2f((unsigned short)(g1.y & 0xffffu)), a2);
        a3 = fmaf(w1, bf2f((unsigned short)(g1.y >> 16)), a3);
        a0 = fmaf(w2, bf2f((unsigned short)(g2.x & 0xffffu)), a0);
        a1 = fmaf(w2, bf2f((unsigned short)(g2.x >> 16)), a1);
        a2 = fmaf(w2, bf2f((unsigned short)(g2.y & 0xffffu)), a2);
        a3 = fmaf(w2, bf2f((unsigned short)(g2.y >> 16)), a3);
        a0 = fmaf(w3, bf2f((unsigned short)(g3.x & 0xffffu)), a0);
        a1 = fmaf(w3, bf2f((unsigned short)(g3.x >> 16)), a1);
        a2 = fmaf(w3, bf2f((unsigned short)(g3.y & 0xffffu)), a2);
        a3 = fmaf(w3, bf2f((unsigned short)(g3.y >> 16)), a3);
    }
    if (k + 7 < e) {
        int2 c0 = sce[k + q];
        int2 c1 = sce[k + 4 + q];
        uint2 g0 = egoV[(size_t)c0.x * 16 + ql];
        uint2 g1 = egoV[(size_t)c1.x * 16 + ql];
        float w0 = __builtin_bit_cast(float, c0.y);
        float w1 = __builtin_bit_cast(float, c1.y);
        a0 = fmaf(w0, bf2f((unsigned short)(g0.x & 0xffffu)), a0);
        a1 = fmaf(w0, bf2f((unsigned short)(g0.x >> 16)), a1);
        a2 = fmaf(w0, bf2f((unsigned short)(g0.y & 0xffffu)), a2);
        a3 = fmaf(w0, bf2f((unsigned short)(g0.y >> 16)), a3);
        a0 = fmaf(w1, bf2f((unsigned short)(g1.x & 0xffffu)), a0);
        a1 = fmaf(w1, bf2f((unsigned short)(g1.x >> 16)), a1);
        a2 = fmaf(w1, bf2f((unsigned short)(g1.y & 0xffffu)), a2);
        a3 = fmaf(w1, bf2f((unsigned short)(g1.y >> 16)), a3);
        k += 8;
    }
    if (k + 3 < e) {
        int2 c0 = sce[k + q];
        uint2 g0 = egoV[(size_t)c0.x * 16 + ql];
        float w0 = __builtin_bit_cast(float, c0.y);
        a0 = fmaf(w0, bf2f((unsigned short)(g0.x & 0xffffu)), a0);
        a1 = fmaf(w0, bf2f((unsigned short)(g0.x >> 16)), a1);
        a2 = fmaf(w0, bf2f((unsigned short)(g0.y & 0xffffu)), a2);
        a3 = fmaf(w0, bf2f((unsigned short)(g0.y >> 16)), a3);
        k += 4;
    }
    if (k < e) {  // remainder 1-3 edges, predicated across quarters
        int idx = k + q;
        bool ok = idx < e;
        int2 c = sce[ok ? idx : (e - 1)];
        float w = ok ? __builtin_bit_cast(float, c.y) : 0.f;
        uint2 g = egoV[(size_t)c.x * 16 + ql];
        a0 = fmaf(w, bf2f((unsigned short)(g.x & 0xffffu)), a0);
        a1 = fmaf(w, bf2f((unsigned short)(g.x >> 16)), a1);
        a2 = fmaf(w, bf2f((unsigned short)(g.y & 0xffffu)), a2);
        a3 = fmaf(w, bf2f((unsigned short)(g.y >> 16)), a3);
    }
    // combine the 4 quarters (quarter bits are lane bits 4 and 5)
    a0 += __shfl_xor(a0, 32, 64); a0 += __shfl_xor(a0, 16, 64);
    a1 += __shfl_xor(a1, 32, 64); a1 += __shfl_xor(a1, 16, 64);
    a2 += __shfl_xor(a2, 32, 64); a2 += __shfl_xor(a2, 16, 64);
    a3 += __shfl_xor(a3, 32, 64); a3 += __shfl_xor(a3, 16, 64);
    if (q == 0) {
        uint2 o;
        o.x = (unsigned)f2bf(a0) | ((unsigned)f2bf(a1) << 16);
        o.y = (unsigned)f2bf(a2) | ((unsigned)f2bf(a3) << 16);
        ((uint2*)side_bf)[(size_t)r * 16 + ql] = o;
    }
}

// ---------------- dense via MFMA bf16, all-bf16 I/O, in-place ego -------
__global__ __launch_bounds__(256) void gemm_dense_kernel(
    unsigned short* __restrict__ ego,            // bf16 in/out
    const unsigned short* __restrict__ side_bf,
    const unsigned short* __restrict__ BT, const float* __restrict__ b1,
    const float* __restrict__ b2, float* __restrict__ nrm) {
    __shared__ unsigned short A_lds[64][136];  // 272B row stride, 16B aligned
    const int tid  = threadIdx.x;
    const int lane = tid & 63, wm = tid >> 6;
    const int m = lane & 15, g = lane >> 4;
    const int base = blockIdx.x * 64;

    bfrag8 b[4][4];
#pragma unroll
    for (int nt = 0; nt < 4; ++nt)
#pragma unroll
        for (int kt = 0; kt < 4; ++kt)
            b[nt][kt] =
                *(const bfrag8*)(BT + (nt * 16 + m) * 128 + kt * 32 + g * 8);

    float bias[4];
#pragma unroll
    for (int nt = 0; nt < 4; ++nt)
        bias[nt] = b1[nt * 16 + m] + b2[nt * 16 + m];

    // stage A tile: sli = ego+side, pr = ego*side (all bf16, 16B loads)
#pragma unroll
    for (int it = 0; it < 2; ++it) {
        int idx = it * 256 + tid;     // 0..511
        int n = idx >> 3, c = idx & 7;  // row, 8-dim chunk
        int node = base + n;
        uint4 ev = make_uint4(0, 0, 0, 0), sv = make_uint4(0, 0, 0, 0);
        if (node < N_NODES) {
            ev = ((const uint4*)ego)[(size_t)node * 8 + c];
            sv = ((const uint4*)side_bf)[(size_t)node * 8 + c];
        }
        unsigned evu[4] = {ev.x, ev.y, ev.z, ev.w};
        unsigned svu[4] = {sv.x, sv.y, sv.z, sv.w};
        unsigned qv[4], pq[4];
#pragma unroll
        for (int j = 0; j < 4; ++j) {
            float e0 = bf2f((unsigned short)(evu[j] & 0xffffu));
            float e1 = bf2f((unsigned short)(evu[j] >> 16));
            float s0 = bf2f((unsigned short)(svu[j] & 0xffffu));
            float s1 = bf2f((unsigned short)(svu[j] >> 16));
            qv[j] = f2bf(e0 + s0) | ((unsigned)f2bf(e1 + s1) << 16);
            pq[j] = f2bf(e0 * s0) | ((unsigned)f2bf(e1 * s1) << 16);
        }
        *(uint4*)&A_lds[n][c * 8]      = make_uint4(qv[0], qv[1], qv[2], qv[3]);
        *(uint4*)&A_lds[n][64 + c * 8] = make_uint4(pq[0], pq[1], pq[2], pq[3]);
    }
    __syncthreads();

    bfrag8 a[4];
#pragma unroll
    for (int kt = 0; kt < 4; ++kt)
        a[kt] = *(const bfrag8*)&A_lds[wm * 16 + m][kt * 32 + g * 8];

    vf4 acc[4];
#pragma unroll
    for (int nt = 0; nt < 4; ++nt) acc[nt] = (vf4){0.f, 0.f, 0.f, 0.f};
#pragma unroll
    for (int kt = 0; kt < 4; ++kt)
#pragma unroll
        for (int nt = 0; nt < 4; ++nt)
            acc[nt] = __builtin_amdgcn_mfma_f32_16x16x32_bf16(
                a[kt], b[nt][kt], acc[nt], 0, 0, 0);

    float o[4][4];
    float sq[4] = {0.f, 0.f, 0.f, 0.f};
#pragma unroll
    for (int nt = 0; nt < 4; ++nt)
#pragma unroll
        for (int r = 0; r < 4; ++r) {
            float v = acc[nt][r] + bias[nt];
            v = (v >= 0.f) ? v : 0.01f * v;
            o[nt][r] = v;
            sq[r] += v * v;
        }
#pragma unroll
    for (int r = 0; r < 4; ++r)
#pragma unroll
        for (int off = 1; off < 16; off <<= 1)
            sq[r] += __shfl_xor(sq[r], off, 64);  // reduce over m (same rows)

#pragma unroll
    for (int r = 0; r < 4; ++r) {
        int row = base + wm * 16 + g * 4 + r;  // C/D: row=(lane>>4)*4+reg
        if (row < N_NODES) {
#pragma unroll
            for (int nt = 0; nt < 4; ++nt)
                ego[(size_t)row * 64 + nt * 16 + m] = f2bf(o[nt][r]);
            if (m == 0) nrm[row] = fmaxf(sqrtf(sq[r]), 1e-12f);
        }
    }
}

// ---------------- batch accumulation over one 64-dim concat segment ------
__global__ __launch_bounds__(256) void batch_kernel(
    const unsigned short* __restrict__ ego_bf, const float* __restrict__ nrm,
    int use_nrm, const int* __restrict__ u, const int* __restrict__ pi,
    const int* __restrict__ ni, float* __restrict__ dot_ui,
    float* __restrict__ dot_uj, float* __restrict__ l2b) {
    const int lane = threadIdx.x & 63;
    int b = (blockIdx.x * blockDim.x + threadIdx.x) >> 6;
    if (b >= BATCH) return;
    int un = u[b];
    int pn = N_USERS + pi[b];
    int nn = N_USERS + ni[b];
    float fu = bf2f(ego_bf[(size_t)un * EMB + lane]);
    float fp = bf2f(ego_bf[(size_t)pn * EMB + lane]);
    float fn_ = bf2f(ego_bf[(size_t)nn * EMB + lane]);
    if (use_nrm) {
        fu /= nrm[un];
        fp /= nrm[pn];
        fn_ /= nrm[nn];
    }
    float dup = fu * fp;
    float dun = fu * fn_;
    float l2  = fu * fu + fp * fp + fn_ * fn_;
#pragma unroll
    for (int off = 32; off; off >>= 1) {
        dup += __shfl_xor(dup, off, 64);
        dun += __shfl_xor(dun, off, 64);
        l2  += __shfl_xor(l2, off, 64);
    }
    if (lane == 0) {
        dot_ui[b] += dup;
        dot_uj[b] += dun;
        l2b[b]    += l2;
    }
}

// ---------------- final scalar reduce ----------------
__global__ __launch_bounds__(256) void final_kernel(
    const float* __restrict__ dot_ui, const float* __restrict__ dot_uj,
    const float* __restrict__ l2b, float* __restrict__ out) {
    __shared__ float sl[256], s2[256];
    float accL = 0.f, acc2 = 0.f;
    for (int b = threadIdx.x; b < BATCH; b += 256) {
        float x = dot_ui[b] - dot_uj[b];
        float sp = (x > 0.f) ? log1pf(expf(-x)) : (-x + log1pf(expf(x)));
        accL += sp;
        acc2 += l2b[b];
    }
    sl[threadIdx.x] = accL;
    s2[threadIdx.x] = acc2;
    __syncthreads();
    for (int off = 128; off; off >>= 1) {
        if (threadIdx.x < off) {
            sl[threadIdx.x] += sl[threadIdx.x + off];
            s2[threadIdx.x] += s2[threadIdx.x + off];
        }
        __syncthreads();
    }
    if (threadIdx.x == 0)
        out[0] = sl[0] / (float)BATCH + REG * (s2[0] * 0.5f / (float)BATCH);
}

extern "C" void kernel_launch(void* const* d_in, const int* in_sizes, int n_in,
                              void* d_out, int out_size, void* d_ws,
                              size_t ws_size, hipStream_t stream) {
    const int*   adj_row  = (const int*)d_in[0];
    const int*   adj_col  = (const int*)d_in[1];
    const float* adj_val  = (const float*)d_in[2];
    const float* user_emb = (const float*)d_in[3];
    const float* item_emb = (const float*)d_in[4];
    const float* W1       = (const float*)d_in[5];
    const float* b1       = (const float*)d_in[6];
    const float* W2       = (const float*)d_in[7];
    const float* b2       = (const float*)d_in[8];
    const int*   u        = (const int*)d_in[9];
    const int*   ii       = (const int*)d_in[10];
    const int*   jj       = (const int*)d_in[11];

    char* p = (char*)d_ws;
    auto alloc = [&](size_t bytes) {
        char* q = p;
        p += (bytes + 255) & ~(size_t)255;
        return q;
    };
    unsigned short* ego    = (unsigned short*)alloc((size_t)N_NODES * EMB * 2);
    unsigned short* side_bf= (unsigned short*)alloc((size_t)N_NODES * EMB * 2);
    int2*           sce    = (int2*)alloc((size_t)NNZ * 8);
    int2*           stage  = (int2*)alloc((size_t)NB_BUCKET * BCAP * 8);
    int*            rp     = (int*)alloc((size_t)(N_NODES + 1) * 4);
    int*            bcnt   = (int*)alloc((size_t)NB_BUCKET * 4);
    int*            bbase  = (int*)alloc((size_t)(NB_BUCKET + 1) * 4);
    float*          nrm    = (float*)alloc((size_t)N_NODES * 4);
    float*          dot_ui = (float*)alloc((size_t)BATCH * 4);
    float*          dot_uj = (float*)alloc((size_t)BATCH * 4);
    float*          l2b    = (float*)alloc((size_t)BATCH * 4);
    unsigned short* BT     = (unsigned short*)alloc((size_t)NLAYERS * 8192 * 2);

    hipMemsetAsync(dot_ui, 0, BATCH * sizeof(float), stream);
    hipMemsetAsync(dot_uj, 0, BATCH * sizeof(float), stream);
    hipMemsetAsync(l2b, 0, BATCH * sizeof(float), stream);
    hipMemsetAsync(bcnt, 0, NB_BUCKET * sizeof(int), stream);

    prep_w_kernel<<<(NLAYERS * 8192 + 255) / 256, 256, 0, stream>>>(W1, W2, BT);

    // ---- build CSR (once; shared by all 3 layers) ----
    binscatter_kernel<<<BIN_NB, 1024, 0, stream>>>(adj_row, adj_col, adj_val,
                                                   bcnt, stage);
    bscan_kernel<<<1, 1024, 0, stream>>>(bcnt, bbase);
    bucket_place_kernel<<<NB_BUCKET, 1024, 0, stream>>>(stage, bcnt, bbase, rp,
                                                        sce);

    init_ego_kernel<<<2048, 256, 0, stream>>>((const float4*)user_emb,
                                              (const float4*)item_emb,
                                              (ushort4*)ego);

    batch_kernel<<<BATCH / 4, 256, 0, stream>>>(ego, nrm, 0, u, ii, jj,
                                                dot_ui, dot_uj, l2b);

    for (int k = 0; k < NLAYERS; ++k) {
        spmm_csr_kernel<<<(N_NODES * 64 + 255) / 256, 256, 0, stream>>>(
            rp, sce, ego, side_bf);
        gemm_dense_kernel<<<NTILES, 256, 0, stream>>>(
            ego, side_bf, BT + (size_t)k * 8192, b1 + (size_t)k * EMB,
            b2 + (size_t)k * EMB, nrm);
        batch_kernel<<<BATCH / 4, 256, 0, stream>>>(ego, nrm, 1, u, ii, jj,
                                                    dot_ui, dot_uj, l2b);
    }

    final_kernel<<<1, 256, 0, stream>>>(dot_ui, dot_uj, l2b, (float*)d_out);
}

// Round 15
// 373.079 us; speedup vs baseline: 3.6500x; 1.1578x over previous
//
#include <hip/hip_runtime.h>

#define N_USERS 100000
#define N_ITEMS 50000
#define N_NODES 150000
#define NNZ     2400000
#define EMB     64
#define NLAYERS 3
#define BATCH   16384
#define REG     1e-5f

#define NTILES ((N_NODES + 63) / 64)  // 2344

#define ROWS_PER_BUCKET 256
#define NB_BUCKET ((N_NODES + ROWS_PER_BUCKET - 1) / ROWS_PER_BUCKET)  // 586
#define BIN_CHUNK 4096
#define BIN_NB ((NNZ + BIN_CHUNK - 1) / BIN_CHUNK)  // 586
#define BCAP 6144   // per-bucket staging capacity: mean 4096, sigma 64

typedef __attribute__((ext_vector_type(8))) short bfrag8;  // 8 bf16 (4 VGPRs)
typedef __attribute__((ext_vector_type(4))) float vf4;     // 4 f32 acc

__device__ inline unsigned short f2bf(float x) {  // f32 -> bf16 RTN-even
    unsigned int u = __builtin_bit_cast(unsigned int, x);
    return (unsigned short)((u + 0x7fffu + ((u >> 16) & 1u)) >> 16);
}
__device__ inline float bf2f(unsigned short h) {
    unsigned int u = ((unsigned int)h) << 16;
    return __builtin_bit_cast(float, u);
}

// ---------------- init: ego_bf = bf16(concat(user_emb, item_emb)) -------
__global__ void init_ego_kernel(const float4* __restrict__ ue,
                                const float4* __restrict__ ie,
                                ushort4* __restrict__ ego_bf) {
    const int n4u = N_USERS * (EMB / 4);
    const int n4  = N_NODES * (EMB / 4);
    for (int t = blockIdx.x * blockDim.x + threadIdx.x; t < n4;
         t += gridDim.x * blockDim.x) {
        float4 v = (t < n4u) ? ue[t] : ie[t - n4u];
        ushort4 h;
        h.x = f2bf(v.x); h.y = f2bf(v.y); h.z = f2bf(v.z); h.w = f2bf(v.w);
        ego_bf[t] = h;
    }
}

// ---------------- prep: BT[layer][j][k] = bf16([W1;W2][k][j]) ------------
__global__ __launch_bounds__(256) void prep_w_kernel(
    const float* __restrict__ W1, const float* __restrict__ W2,
    unsigned short* __restrict__ BT) {
    int idx = blockIdx.x * blockDim.x + threadIdx.x;
    if (idx >= NLAYERS * 64 * 128) return;
    int l = idx / 8192;
    int rem = idx - l * 8192;
    int j = rem >> 7;        // output dim (row of BT)
    int k = rem & 127;       // concat-K
    float w = (k < 64) ? W1[l * 4096 + k * 64 + j]
                       : W2[l * 4096 + (k - 64) * 64 + j];
    BT[idx] = f2bf(w);
}

// ---------------- pass A: bucket-binned scatter (fixed-cap regions) -----
__global__ __launch_bounds__(1024) void binscatter_kernel(
    const int* __restrict__ row, const int* __restrict__ col,
    const float* __restrict__ val, int* __restrict__ bcnt,
    int2* __restrict__ stage) {
    __shared__ int hist[NB_BUCKET];
    __shared__ int wbase[NB_BUCKET];
    const int t = threadIdx.x;
    const int s = blockIdx.x * BIN_CHUNK;
    const int e = min(s + BIN_CHUNK, NNZ);

    for (int b = t; b < NB_BUCKET; b += 1024) hist[b] = 0;
    __syncthreads();
    for (int i = s + t; i < e; i += 1024)
        atomicAdd(&hist[row[i] >> 8], 1);
    __syncthreads();
    for (int b = t; b < NB_BUCKET; b += 1024) {
        int c = hist[b];
        wbase[b] = c ? atomicAdd(&bcnt[b], c) : 0;
        hist[b] = 0;  // reuse as local cursor
    }
    __syncthreads();
    for (int i = s + t; i < e; i += 1024) {
        int r = row[i];
        int b = r >> 8;
        int off = atomicAdd(&hist[b], 1);
        stage[(size_t)b * BCAP + wbase[b] + off] =
            make_int2(col[i] | ((r & 255) << 18),
                      __builtin_bit_cast(int, val[i]));
    }
}

// ---------------- bucket scan: CSR bases from measured counts -----------
__global__ __launch_bounds__(1024) void bscan_kernel(
    const int* __restrict__ bcnt, int* __restrict__ bbase) {
    __shared__ int sc[1024];
    const int t = threadIdx.x;
    int v = (t < NB_BUCKET) ? bcnt[t] : 0;
    sc[t] = v;
    __syncthreads();
    int x = v;
    for (int off = 1; off < 1024; off <<= 1) {
        int y = (t >= off) ? sc[t - off] : 0;
        __syncthreads();
        x += y;
        sc[t] = x;
        __syncthreads();
    }
    if (t < NB_BUCKET) bbase[t] = x - v;  // exclusive
    if (t == 0) bbase[NB_BUCKET] = NNZ;
}

// ---------------- pass B: row-count + scan + CSR placement --------------
__global__ __launch_bounds__(1024) void bucket_place_kernel(
    const int2* __restrict__ stage, const int* __restrict__ bcnt,
    const int* __restrict__ bbase, int* __restrict__ rp,
    int2* __restrict__ sce) {
    __shared__ int cnt[ROWS_PER_BUCKET];
    __shared__ int sc[ROWS_PER_BUCKET];
    __shared__ int cur[ROWS_PER_BUCKET];
    const int b = blockIdx.x;
    const int t = threadIdx.x;
    const int row0 = b * ROWS_PER_BUCKET;
    const size_t S0 = (size_t)b * BCAP;
    const int ne = bcnt[b];
    const int B0 = bbase[b];
    if (t < 256) cnt[t] = 0;
    __syncthreads();
    for (int i = t; i < ne; i += 1024)
        atomicAdd(&cnt[(stage[S0 + i].x >> 18) & 255], 1);
    __syncthreads();
    int v = 0, x = 0;
    if (t < 256) { v = cnt[t]; x = v; sc[t] = v; }
    __syncthreads();
    for (int off = 1; off < 256; off <<= 1) {
        int y = (t < 256 && t >= off) ? sc[t - off] : 0;
        __syncthreads();
        if (t < 256) { x += y; sc[t] = x; }
        __syncthreads();
    }
    if (t < 256) {
        int excl = x - v;
        int row = row0 + t;
        if (row <= N_NODES) rp[row] = B0 + excl;  // row==N_NODES -> NNZ
        cur[t] = B0 + excl;
    }
    __syncthreads();
    for (int i = t; i < ne; i += 1024) {
        int2 pk = stage[S0 + i];
        int rl = (pk.x >> 18) & 255;
        int pos = atomicAdd(&cur[rl], 1);
        sce[pos] = make_int2(pk.x & 0x3FFFF, pk.y);
    }
}

// ---------------- CSR SpMM: quarter-wave per edge, 4 dims/lane ----------
__global__ __launch_bounds__(256) void spmm_csr_kernel(
    const int* __restrict__ rp, const int2* __restrict__ sce,
    const unsigned short* __restrict__ ego_bf,
    unsigned short* __restrict__ side_bf) {
    const int lane = threadIdx.x & 63;
    const int q    = lane >> 4;   // which edge of the 4-group
    const int ql   = lane & 15;   // dim-quad index (dims 4ql..4ql+3)
    int r = (blockIdx.x * blockDim.x + threadIdx.x) >> 6;
    if (r >= N_NODES) return;
    const uint2* egoV = (const uint2*)ego_bf;  // row stride 16 uint2
    int s = rp[r], e = rp[r + 1];
    float a0 = 0.f, a1 = 0.f, a2 = 0.f, a3 = 0.f;
    int k = s;
    for (; k + 15 < e; k += 16) {
        int2 c0 = sce[k + q];
        int2 c1 = sce[k + 4 + q];
        int2 c2 = sce[k + 8 + q];
        int2 c3 = sce[k + 12 + q];
        uint2 g0 = egoV[(size_t)c0.x * 16 + ql];
        uint2 g1 = egoV[(size_t)c1.x * 16 + ql];
        uint2 g2 = egoV[(size_t)c2.x * 16 + ql];
        uint2 g3 = egoV[(size_t)c3.x * 16 + ql];
        float w0 = __builtin_bit_cast(float, c0.y);
        float w1 = __builtin_bit_cast(float, c1.y);
        float w2 = __builtin_bit_cast(float, c2.y);
        float w3 = __builtin_bit_cast(float, c3.y);
        a0 = fmaf(w0, bf2f((unsigned short)(g0.x & 0xffffu)), a0);
        a1 = fmaf(w0, bf2f((unsigned short)(g0.x >> 16)), a1);
        a2 = fmaf(w0, bf2f((unsigned short)(g0.y & 0xffffu)), a2);
        a3 = fmaf(w0, bf2f((unsigned short)(g0.y >> 16)), a3);
        a0 = fmaf(w1, bf2f((unsigned short)(g1.x & 0xffffu)), a0);
        a1 = fmaf(w1, bf2f((unsigned short)(g1.x >> 16)), a1);
        a2 = fmaf(w1, bf2f((unsigned short)(g1.y & 0xffffu)), a2);
        a3 = fmaf(w1, bf2f((unsigned short)(g1.y >> 16)), a3);
        a0 = fmaf(w2, bf2f((unsigned short)(g2.x & 0xffffu)), a0);
        a1 = fmaf(w2, bf2f((unsigned short)(g2.x >> 16)), a1);
        a2 = fmaf(w2, bf2f((unsigned short)(g2.y & 0xffffu)), a2);
        a3 = fmaf(w2, bf2f((unsigned short)(g2.y >> 16)), a3);
        a0 = fmaf(w3, bf2f((unsigned short)(g3.x & 0xffffu)), a0);
        a1 = fmaf(w3, bf2f((unsigned short)(g3.x >> 16)), a1);
        a2 = fmaf(w3, bf2f((unsigned short)(g3.y & 0xffffu)), a2);
        a3 = fmaf(w3, bf2f((unsigned short)(g3.y >> 16)), a3);
    }
    if (k + 7 < e) {
        int2 c0 = sce[k + q];
        int2 c1 = sce[k + 4 + q];
        uint2 g0 = egoV[(size_t)c0.x * 16 + ql];
        uint2 g1 = egoV[(size_t)c1.x * 16 + ql];
        float w0 = __builtin_bit_cast(float, c0.y);
        float w1 = __builtin_bit_cast(float, c1.y);
        a0 = fmaf(w0, bf2f((unsigned short)(g0.x & 0xffffu)), a0);
        a1 = fmaf(w0, bf2f((unsigned short)(g0.x >> 16)), a1);
        a2 = fmaf(w0, bf2f((unsigned short)(g0.y & 0xffffu)), a2);
        a3 = fmaf(w0, bf2f((unsigned short)(g0.y >> 16)), a3);
        a0 = fmaf(w1, bf2f((unsigned short)(g1.x & 0xffffu)), a0);
        a1 = fmaf(w1, bf2f((unsigned short)(g1.x >> 16)), a1);
        a2 = fmaf(w1, bf2f((unsigned short)(g1.y & 0xffffu)), a2);
        a3 = fmaf(w1, bf2f((unsigned short)(g1.y >> 16)), a3);
        k += 8;
    }
    if (k + 3 < e) {
        int2 c0 = sce[k + q];
        uint2 g0 = egoV[(size_t)c0.x * 16 + ql];
        float w0 = __builtin_bit_cast(float, c0.y);
        a0 = fmaf(w0, bf2f((unsigned short)(g0.x & 0xffffu)), a0);
        a1 = fmaf(w0, bf2f((unsigned short)(g0.x >> 16)), a1);
        a2 = fmaf(w0, bf2f((unsigned short)(g0.y & 0xffffu)), a2);
        a3 = fmaf(w0, bf2f((unsigned short)(g0.y >> 16)), a3);
        k += 4;
    }
    if (k < e) {  // remainder 1-3 edges, predicated across quarters
        int idx = k + q;
        bool ok = idx < e;
        int2 c = sce[ok ? idx : (e - 1)];
        float w = ok ? __builtin_bit_cast(float, c.y) : 0.f;
        uint2 g = egoV[(size_t)c.x * 16 + ql];
        a0 = fmaf(w, bf2f((unsigned short)(g.x & 0xffffu)), a0);
        a1 = fmaf(w, bf2f((unsigned short)(g.x >> 16)), a1);
        a2 = fmaf(w, bf2f((unsigned short)(g.y & 0xffffu)), a2);
        a3 = fmaf(w, bf2f((unsigned short)(g.y >> 16)), a3);
    }
    // combine the 4 quarters (quarter bits are lane bits 4 and 5)
    a0 += __shfl_xor(a0, 32, 64); a0 += __shfl_xor(a0, 16, 64);
    a1 += __shfl_xor(a1, 32, 64); a1 += __shfl_xor(a1, 16, 64);
    a2 += __shfl_xor(a2, 32, 64); a2 += __shfl_xor(a2, 16, 64);
    a3 += __shfl_xor(a3, 32, 64); a3 += __shfl_xor(a3, 16, 64);
    if (q == 0) {
        uint2 o;
        o.x = (unsigned)f2bf(a0) | ((unsigned)f2bf(a1) << 16);
        o.y = (unsigned)f2bf(a2) | ((unsigned)f2bf(a3) << 16);
        ((uint2*)side_bf)[(size_t)r * 16 + ql] = o;
    }
}

// ---------------- dense via MFMA bf16, all-bf16 I/O, in-place ego -------
__global__ __launch_bounds__(256) void gemm_dense_kernel(
    unsigned short* __restrict__ ego,            // bf16 in/out
    const unsigned short* __restrict__ side_bf,
    const unsigned short* __restrict__ BT, const float* __restrict__ b1,
    const float* __restrict__ b2, float* __restrict__ nrm) {
    __shared__ unsigned short A_lds[64][136];  // 272B row stride, 16B aligned
    const int tid  = threadIdx.x;
    const int lane = tid & 63, wm = tid >> 6;
    const int m = lane & 15, g = lane >> 4;
    const int base = blockIdx.x * 64;

    bfrag8 b[4][4];
#pragma unroll
    for (int nt = 0; nt < 4; ++nt)
#pragma unroll
        for (int kt = 0; kt < 4; ++kt)
            b[nt][kt] =
                *(const bfrag8*)(BT + (nt * 16 + m) * 128 + kt * 32 + g * 8);

    float bias[4];
#pragma unroll
    for (int nt = 0; nt < 4; ++nt)
        bias[nt] = b1[nt * 16 + m] + b2[nt * 16 + m];

    // stage A tile: sli = ego+side, pr = ego*side (all bf16, 16B loads)
#pragma unroll
    for (int it = 0; it < 2; ++it) {
        int idx = it * 256 + tid;     // 0..511
        int n = idx >> 3, c = idx & 7;  // row, 8-dim chunk
        int node = base + n;
        uint4 ev = make_uint4(0, 0, 0, 0), sv = make_uint4(0, 0, 0, 0);
        if (node < N_NODES) {
            ev = ((const uint4*)ego)[(size_t)node * 8 + c];
            sv = ((const uint4*)side_bf)[(size_t)node * 8 + c];
        }
        unsigned evu[4] = {ev.x, ev.y, ev.z, ev.w};
        unsigned svu[4] = {sv.x, sv.y, sv.z, sv.w};
        unsigned qv[4], pq[4];
#pragma unroll
        for (int j = 0; j < 4; ++j) {
            float e0 = bf2f((unsigned short)(evu[j] & 0xffffu));
            float e1 = bf2f((unsigned short)(evu[j] >> 16));
            float s0 = bf2f((unsigned short)(svu[j] & 0xffffu));
            float s1 = bf2f((unsigned short)(svu[j] >> 16));
            qv[j] = f2bf(e0 + s0) | ((unsigned)f2bf(e1 + s1) << 16);
            pq[j] = f2bf(e0 * s0) | ((unsigned)f2bf(e1 * s1) << 16);
        }
        *(uint4*)&A_lds[n][c * 8]      = make_uint4(qv[0], qv[1], qv[2], qv[3]);
        *(uint4*)&A_lds[n][64 + c * 8] = make_uint4(pq[0], pq[1], pq[2], pq[3]);
    }
    __syncthreads();

    bfrag8 a[4];
#pragma unroll
    for (int kt = 0; kt < 4; ++kt)
        a[kt] = *(const bfrag8*)&A_lds[wm * 16 + m][kt * 32 + g * 8];

    vf4 acc[4];
#pragma unroll
    for (int nt = 0; nt < 4; ++nt) acc[nt] = (vf4){0.f, 0.f, 0.f, 0.f};
#pragma unroll
    for (int kt = 0; kt < 4; ++kt)
#pragma unroll
        for (int nt = 0; nt < 4; ++nt)
            acc[nt] = __builtin_amdgcn_mfma_f32_16x16x32_bf16(
                a[kt], b[nt][kt], acc[nt], 0, 0, 0);

    float o[4][4];
    float sq[4] = {0.f, 0.f, 0.f, 0.f};
#pragma unroll
    for (int nt = 0; nt < 4; ++nt)
#pragma unroll
        for (int r = 0; r < 4; ++r) {
            float v = acc[nt][r] + bias[nt];
            v = (v >= 0.f) ? v : 0.01f * v;
            o[nt][r] = v;
            sq[r] += v * v;
        }
#pragma unroll
    for (int r = 0; r < 4; ++r)
#pragma unroll
        for (int off = 1; off < 16; off <<= 1)
            sq[r] += __shfl_xor(sq[r], off, 64);  // reduce over m (same rows)

#pragma unroll
    for (int r = 0; r < 4; ++r) {
        int row = base + wm * 16 + g * 4 + r;  // C/D: row=(lane>>4)*4+reg
        if (row < N_NODES) {
#pragma unroll
            for (int nt = 0; nt < 4; ++nt)
                ego[(size_t)row * 64 + nt * 16 + m] = f2bf(o[nt][r]);
            if (m == 0) nrm[row] = fmaxf(sqrtf(sq[r]), 1e-12f);
        }
    }
}

// ---------------- batch accumulation over one 64-dim concat segment ------
__global__ __launch_bounds__(256) void batch_kernel(
    const unsigned short* __restrict__ ego_bf, const float* __restrict__ nrm,
    int use_nrm, const int* __restrict__ u, const int* __restrict__ pi,
    const int* __restrict__ ni, float* __restrict__ dot_ui,
    float* __restrict__ dot_uj, float* __restrict__ l2b) {
    const int lane = threadIdx.x & 63;
    int b = (blockIdx.x * blockDim.x + threadIdx.x) >> 6;
    if (b >= BATCH) return;
    int un = u[b];
    int pn = N_USERS + pi[b];
    int nn = N_USERS + ni[b];
    float fu = bf2f(ego_bf[(size_t)un * EMB + lane]);
    float fp = bf2f(ego_bf[(size_t)pn * EMB + lane]);
    float fn_ = bf2f(ego_bf[(size_t)nn * EMB + lane]);
    if (use_nrm) {
        fu /= nrm[un];
        fp /= nrm[pn];
        fn_ /= nrm[nn];
    }
    float dup = fu * fp;
    float dun = fu * fn_;
    float l2  = fu * fu + fp * fp + fn_ * fn_;
#pragma unroll
    for (int off = 32; off; off >>= 1) {
        dup += __shfl_xor(dup, off, 64);
        dun += __shfl_xor(dun, off, 64);
        l2  += __shfl_xor(l2, off, 64);
    }
    if (lane == 0) {
        dot_ui[b] += dup;
        dot_uj[b] += dun;
        l2b[b]    += l2;
    }
}

// ---------------- loss stage 1: parallel softplus + block partials ------
__global__ __launch_bounds__(256) void loss_partial_kernel(
    const float* __restrict__ dot_ui, const float* __restrict__ dot_uj,
    const float* __restrict__ l2b, float* __restrict__ partial) {
    __shared__ float sl[256], s2[256];
    const int t = threadIdx.x;
    const int b = blockIdx.x * 256 + t;  // 64 blocks x 256 = 16384 = BATCH
    float x = dot_ui[b] - dot_uj[b];
    float sp = (x > 0.f) ? log1pf(expf(-x)) : (-x + log1pf(expf(x)));
    sl[t] = sp;
    s2[t] = l2b[b];
    __syncthreads();
    for (int off = 128; off; off >>= 1) {
        if (t < off) {
            sl[t] += sl[t + off];
            s2[t] += s2[t + off];
        }
        __syncthreads();
    }
    if (t == 0) {
        partial[blockIdx.x]      = sl[0];
        partial[64 + blockIdx.x] = s2[0];
    }
}

// ---------------- loss stage 2: one wave reduces 64 partials ------------
__global__ void loss_final_kernel(const float* __restrict__ partial,
                                  float* __restrict__ out) {
    const int t = threadIdx.x;  // 64 threads
    float sp = partial[t];
    float l2 = partial[64 + t];
#pragma unroll
    for (int off = 32; off; off >>= 1) {
        sp += __shfl_down(sp, off, 64);
        l2 += __shfl_down(l2, off, 64);
    }
    if (t == 0)
        out[0] = sp / (float)BATCH + REG * (l2 * 0.5f / (float)BATCH);
}

extern "C" void kernel_launch(void* const* d_in, const int* in_sizes, int n_in,
                              void* d_out, int out_size, void* d_ws,
                              size_t ws_size, hipStream_t stream) {
    const int*   adj_row  = (const int*)d_in[0];
    const int*   adj_col  = (const int*)d_in[1];
    const float* adj_val  = (const float*)d_in[2];
    const float* user_emb = (const float*)d_in[3];
    const float* item_emb = (const float*)d_in[4];
    const float* W1       = (const float*)d_in[5];
    const float* b1       = (const float*)d_in[6];
    const float* W2       = (const float*)d_in[7];
    const float* b2       = (const float*)d_in[8];
    const int*   u        = (const int*)d_in[9];
    const int*   ii       = (const int*)d_in[10];
    const int*   jj       = (const int*)d_in[11];

    char* p = (char*)d_ws;
    auto alloc = [&](size_t bytes) {
        char* q = p;
        p += (bytes + 255) & ~(size_t)255;
        return q;
    };
    unsigned short* ego    = (unsigned short*)alloc((size_t)N_NODES * EMB * 2);
    unsigned short* side_bf= (unsigned short*)alloc((size_t)N_NODES * EMB * 2);
    int2*           sce    = (int2*)alloc((size_t)NNZ * 8);
    int2*           stage  = (int2*)alloc((size_t)NB_BUCKET * BCAP * 8);
    int*            rp     = (int*)alloc((size_t)(N_NODES + 1) * 4);
    int*            bcnt   = (int*)alloc((size_t)NB_BUCKET * 4);
    int*            bbase  = (int*)alloc((size_t)(NB_BUCKET + 1) * 4);
    float*          nrm    = (float*)alloc((size_t)N_NODES * 4);
    float*          dot_ui = (float*)alloc((size_t)BATCH * 4);
    float*          dot_uj = (float*)alloc((size_t)BATCH * 4);
    float*          l2b    = (float*)alloc((size_t)BATCH * 4);
    float*          partial= (float*)alloc(128 * 4);
    unsigned short* BT     = (unsigned short*)alloc((size_t)NLAYERS * 8192 * 2);

    hipMemsetAsync(dot_ui, 0, BATCH * sizeof(float), stream);
    hipMemsetAsync(dot_uj, 0, BATCH * sizeof(float), stream);
    hipMemsetAsync(l2b, 0, BATCH * sizeof(float), stream);
    hipMemsetAsync(bcnt, 0, NB_BUCKET * sizeof(int), stream);

    prep_w_kernel<<<(NLAYERS * 8192 + 255) / 256, 256, 0, stream>>>(W1, W2, BT);

    // ---- build CSR (once; shared by all 3 layers) ----
    binscatter_kernel<<<BIN_NB, 1024, 0, stream>>>(adj_row, adj_col, adj_val,
                                                   bcnt, stage);
    bscan_kernel<<<1, 1024, 0, stream>>>(bcnt, bbase);
    bucket_place_kernel<<<NB_BUCKET, 1024, 0, stream>>>(stage, bcnt, bbase, rp,
                                                        sce);

    init_ego_kernel<<<2048, 256, 0, stream>>>((const float4*)user_emb,
                                              (const float4*)item_emb,
                                              (ushort4*)ego);

    batch_kernel<<<BATCH / 4, 256, 0, stream>>>(ego, nrm, 0, u, ii, jj,
                                                dot_ui, dot_uj, l2b);

    for (int k = 0; k < NLAYERS; ++k) {
        spmm_csr_kernel<<<(N_NODES * 64 + 255) / 256, 256, 0, stream>>>(
            rp, sce, ego, side_bf);
        gemm_dense_kernel<<<NTILES, 256, 0, stream>>>(
            ego, side_bf, BT + (size_t)k * 8192, b1 + (size_t)k * EMB,
            b2 + (size_t)k * EMB, nrm);
        batch_kernel<<<BATCH / 4, 256, 0, stream>>>(ego, nrm, 1, u, ii, jj,
                                                    dot_ui, dot_uj, l2b);
    }

    loss_partial_kernel<<<BATCH / 256, 256, 0, stream>>>(dot_ui, dot_uj, l2b,
                                                         partial);
    loss_final_kernel<<<1, 64, 0, stream>>>(partial, (float*)d_out);
}

// Round 16
// 368.092 us; speedup vs baseline: 3.6995x; 1.0136x over previous
//
#include <hip/hip_runtime.h>

#define N_USERS 100000
#define N_ITEMS 50000
#define N_NODES 150000
#define NNZ     2400000
#define EMB     64
#define NLAYERS 3
#define BATCH   16384
#define REG     1e-5f

#define NTILES ((N_NODES + 63) / 64)  // 2344

#define ROWS_PER_BUCKET 256
#define NB_BUCKET ((N_NODES + ROWS_PER_BUCKET - 1) / ROWS_PER_BUCKET)  // 586
#define BIN_CHUNK 4096
#define BIN_NB ((NNZ + BIN_CHUNK - 1) / BIN_CHUNK)  // 586
#define BCAP 6144   // per-bucket staging capacity: mean 4096, sigma 64

// fp8 mirror scale: keeps values out of the e4m3 denormal zone
#define F8_SCALE 16.0f
#define F8_INV   0.0625f

typedef __attribute__((ext_vector_type(8))) short bfrag8;  // 8 bf16 (4 VGPRs)
typedef __attribute__((ext_vector_type(4))) float vf4;     // 4 f32 acc
typedef __attribute__((ext_vector_type(2))) float f32x2;

// Slot layout: slot p = 4*q + j  <->  dim 16*j + q  (q in [0,16), j in [0,4))
// ego_bf / ego_f8 / side_bf are all stored in slot order; BT's k-axis is
// permuted identically in prep_w, so the MFMA dot (sum over k) is unchanged.
// batch/nrm are full-row reductions (permutation invariant).

__device__ inline unsigned short f2bf(float x) {  // f32 -> bf16 RTN-even
    unsigned int u = __builtin_bit_cast(unsigned int, x);
    return (unsigned short)((u + 0x7fffu + ((u >> 16) & 1u)) >> 16);
}
__device__ inline float bf2f(unsigned short h) {
    unsigned int u = ((unsigned int)h) << 16;
    return __builtin_bit_cast(float, u);
}

// ---------------- init: ego_bf + ego_f8 (slot layout) ----------------
// thread = (row, q): slots 4q..4q+3 = dims {q, 16+q, 32+q, 48+q}
__global__ __launch_bounds__(256) void init_ego_kernel(
    const float* __restrict__ ue, const float* __restrict__ ie,
    unsigned short* __restrict__ ego_bf, unsigned char* __restrict__ ego_f8) {
    int idx = blockIdx.x * 256 + threadIdx.x;
    if (idx >= N_NODES * 16) return;
    int row = idx >> 4, q = idx & 15;
    const float* src = (row < N_USERS)
                           ? ue + (size_t)row * 64
                           : ie + (size_t)(row - N_USERS) * 64;
    float v0 = src[q], v1 = src[16 + q], v2 = src[32 + q], v3 = src[48 + q];
    uint2 o;
    o.x = (unsigned)f2bf(v0) | ((unsigned)f2bf(v1) << 16);
    o.y = (unsigned)f2bf(v2) | ((unsigned)f2bf(v3) << 16);
    ((uint2*)ego_bf)[(size_t)row * 16 + q] = o;
    int u = __builtin_amdgcn_cvt_pk_fp8_f32(v0 * F8_SCALE, v1 * F8_SCALE, 0,
                                            false);
    u = __builtin_amdgcn_cvt_pk_fp8_f32(v2 * F8_SCALE, v3 * F8_SCALE, u, true);
    ((int*)ego_f8)[(size_t)row * 16 + q] = u;
}

// ---------------- prep: BT[l][j][k] = bf16(W[dim(k)][j]), k slot-permuted
__global__ __launch_bounds__(256) void prep_w_kernel(
    const float* __restrict__ W1, const float* __restrict__ W2,
    unsigned short* __restrict__ BT) {
    int idx = blockIdx.x * blockDim.x + threadIdx.x;
    if (idx >= NLAYERS * 64 * 128) return;
    int l = idx / 8192;
    int rem = idx - l * 8192;
    int j = rem >> 7;        // output dim (row of BT)
    int k = rem & 127;       // concat-K slot
    int p = k & 63;
    int d = ((p & 3) << 4) | (p >> 2);  // true dim of slot p
    float w = (k < 64) ? W1[l * 4096 + d * 64 + j]
                       : W2[l * 4096 + d * 64 + j];
    BT[idx] = f2bf(w);
}

// ---------------- pass A: bucket-binned scatter (fixed-cap regions) -----
__global__ __launch_bounds__(1024) void binscatter_kernel(
    const int* __restrict__ row, const int* __restrict__ col,
    const float* __restrict__ val, int* __restrict__ bcnt,
    int2* __restrict__ stage) {
    __shared__ int hist[NB_BUCKET];
    __shared__ int wbase[NB_BUCKET];
    const int t = threadIdx.x;
    const int s = blockIdx.x * BIN_CHUNK;
    const int e = min(s + BIN_CHUNK, NNZ);

    for (int b = t; b < NB_BUCKET; b += 1024) hist[b] = 0;
    __syncthreads();
    for (int i = s + t; i < e; i += 1024)
        atomicAdd(&hist[row[i] >> 8], 1);
    __syncthreads();
    for (int b = t; b < NB_BUCKET; b += 1024) {
        int c = hist[b];
        wbase[b] = c ? atomicAdd(&bcnt[b], c) : 0;
        hist[b] = 0;  // reuse as local cursor
    }
    __syncthreads();
    for (int i = s + t; i < e; i += 1024) {
        int r = row[i];
        int b = r >> 8;
        int off = atomicAdd(&hist[b], 1);
        stage[(size_t)b * BCAP + wbase[b] + off] =
            make_int2(col[i] | ((r & 255) << 18),
                      __builtin_bit_cast(int, val[i]));
    }
}

// ---------------- bucket scan: CSR bases from measured counts -----------
__global__ __launch_bounds__(1024) void bscan_kernel(
    const int* __restrict__ bcnt, int* __restrict__ bbase) {
    __shared__ int sc[1024];
    const int t = threadIdx.x;
    int v = (t < NB_BUCKET) ? bcnt[t] : 0;
    sc[t] = v;
    __syncthreads();
    int x = v;
    for (int off = 1; off < 1024; off <<= 1) {
        int y = (t >= off) ? sc[t - off] : 0;
        __syncthreads();
        x += y;
        sc[t] = x;
        __syncthreads();
    }
    if (t < NB_BUCKET) bbase[t] = x - v;  // exclusive
    if (t == 0) bbase[NB_BUCKET] = NNZ;
}

// ---------------- pass B: row-count + scan + CSR placement --------------
__global__ __launch_bounds__(1024) void bucket_place_kernel(
    const int2* __restrict__ stage, const int* __restrict__ bcnt,
    const int* __restrict__ bbase, int* __restrict__ rp,
    int2* __restrict__ sce) {
    __shared__ int cnt[ROWS_PER_BUCKET];
    __shared__ int sc[ROWS_PER_BUCKET];
    __shared__ int cur[ROWS_PER_BUCKET];
    const int b = blockIdx.x;
    const int t = threadIdx.x;
    const int row0 = b * ROWS_PER_BUCKET;
    const size_t S0 = (size_t)b * BCAP;
    const int ne = bcnt[b];
    const int B0 = bbase[b];
    if (t < 256) cnt[t] = 0;
    __syncthreads();
    for (int i = t; i < ne; i += 1024)
        atomicAdd(&cnt[(stage[S0 + i].x >> 18) & 255], 1);
    __syncthreads();
    int v = 0, x = 0;
    if (t < 256) { v = cnt[t]; x = v; sc[t] = v; }
    __syncthreads();
    for (int off = 1; off < 256; off <<= 1) {
        int y = (t < 256 && t >= off) ? sc[t - off] : 0;
        __syncthreads();
        if (t < 256) { x += y; sc[t] = x; }
        __syncthreads();
    }
    if (t < 256) {
        int excl = x - v;
        int row = row0 + t;
        if (row <= N_NODES) rp[row] = B0 + excl;  // row==N_NODES -> NNZ
        cur[t] = B0 + excl;
    }
    __syncthreads();
    for (int i = t; i < ne; i += 1024) {
        int2 pk = stage[S0 + i];
        int rl = (pk.x >> 18) & 255;
        int pos = atomicAdd(&cur[rl], 1);
        sce[pos] = make_int2(pk.x & 0x3FFFF, pk.y);
    }
}

// ---------------- CSR SpMM: quarter-wave, fp8 gathers (64B rows) --------
// Group q (16 lanes) reads edge (k+q)'s fp8 row: 16 lanes x 4B = 64B.
// Decode via HW v_cvt_pk_f32_fp8 (2 instr -> 4 floats). Accumulate slots
// 4ql..4ql+3 in f32; reduce across quarters; lanes of group 0 store bf16.
__global__ __launch_bounds__(256) void spmm_csr_kernel(
    const int* __restrict__ rp, const int2* __restrict__ sce,
    const unsigned char* __restrict__ ego_f8,
    unsigned short* __restrict__ side_bf) {
    const int lane = threadIdx.x & 63;
    const int q    = lane >> 4;   // which edge of the 4-group
    const int ql   = lane & 15;   // slot-quad index
    int r = (blockIdx.x * blockDim.x + threadIdx.x) >> 6;
    if (r >= N_NODES) return;
    const int* egoF = (const int*)ego_f8;  // row stride 16 ints
    int s = rp[r], e = rp[r + 1];
    float a0 = 0.f, a1 = 0.f, a2 = 0.f, a3 = 0.f;
    int k = s;
#define F8_ACC(gi, wi)                                                       \
    {                                                                        \
        f32x2 lo_ = __builtin_amdgcn_cvt_pk_f32_fp8(gi, false);              \
        f32x2 hi_ = __builtin_amdgcn_cvt_pk_f32_fp8(gi, true);               \
        a0 = fmaf(wi, lo_.x, a0);                                            \
        a1 = fmaf(wi, lo_.y, a1);                                            \
        a2 = fmaf(wi, hi_.x, a2);                                            \
        a3 = fmaf(wi, hi_.y, a3);                                            \
    }
    for (; k + 15 < e; k += 16) {
        int2 c0 = sce[k + q];
        int2 c1 = sce[k + 4 + q];
        int2 c2 = sce[k + 8 + q];
        int2 c3 = sce[k + 12 + q];
        int g0 = egoF[(size_t)c0.x * 16 + ql];
        int g1 = egoF[(size_t)c1.x * 16 + ql];
        int g2 = egoF[(size_t)c2.x * 16 + ql];
        int g3 = egoF[(size_t)c3.x * 16 + ql];
        float w0 = __builtin_bit_cast(float, c0.y);
        float w1 = __builtin_bit_cast(float, c1.y);
        float w2 = __builtin_bit_cast(float, c2.y);
        float w3 = __builtin_bit_cast(float, c3.y);
        F8_ACC(g0, w0) F8_ACC(g1, w1) F8_ACC(g2, w2) F8_ACC(g3, w3)
    }
    if (k + 7 < e) {
        int2 c0 = sce[k + q];
        int2 c1 = sce[k + 4 + q];
        int g0 = egoF[(size_t)c0.x * 16 + ql];
        int g1 = egoF[(size_t)c1.x * 16 + ql];
        float w0 = __builtin_bit_cast(float, c0.y);
        float w1 = __builtin_bit_cast(float, c1.y);
        F8_ACC(g0, w0) F8_ACC(g1, w1)
        k += 8;
    }
    if (k + 3 < e) {
        int2 c0 = sce[k + q];
        int g0 = egoF[(size_t)c0.x * 16 + ql];
        float w0 = __builtin_bit_cast(float, c0.y);
        F8_ACC(g0, w0)
        k += 4;
    }
    if (k < e) {  // remainder 1-3 edges, predicated across quarters
        int idx = k + q;
        bool ok = idx < e;
        int2 c = sce[ok ? idx : (e - 1)];
        float w = ok ? __builtin_bit_cast(float, c.y) : 0.f;
        int g = egoF[(size_t)c.x * 16 + ql];
        F8_ACC(g, w)
    }
#undef F8_ACC
    // combine the 4 quarters (quarter bits are lane bits 4 and 5)
    a0 += __shfl_xor(a0, 32, 64); a0 += __shfl_xor(a0, 16, 64);
    a1 += __shfl_xor(a1, 32, 64); a1 += __shfl_xor(a1, 16, 64);
    a2 += __shfl_xor(a2, 32, 64); a2 += __shfl_xor(a2, 16, 64);
    a3 += __shfl_xor(a3, 32, 64); a3 += __shfl_xor(a3, 16, 64);
    if (q == 0) {
        a0 *= F8_INV; a1 *= F8_INV; a2 *= F8_INV; a3 *= F8_INV;
        uint2 o;
        o.x = (unsigned)f2bf(a0) | ((unsigned)f2bf(a1) << 16);
        o.y = (unsigned)f2bf(a2) | ((unsigned)f2bf(a3) << 16);
        ((uint2*)side_bf)[(size_t)r * 16 + ql] = o;
    }
}

// ---------------- dense via MFMA bf16 (slot layout everywhere) ----------
__global__ __launch_bounds__(256) void gemm_dense_kernel(
    unsigned short* __restrict__ ego,            // bf16 in/out, slot order
    unsigned char* __restrict__ ego_f8,          // fp8 mirror out
    const unsigned short* __restrict__ side_bf,  // slot order
    const unsigned short* __restrict__ BT, const float* __restrict__ b1,
    const float* __restrict__ b2, float* __restrict__ nrm) {
    __shared__ unsigned short A_lds[64][136];  // 272B row stride, 16B aligned
    const int tid  = threadIdx.x;
    const int lane = tid & 63, wm = tid >> 6;
    const int m = lane & 15, g = lane >> 4;
    const int base = blockIdx.x * 64;

    bfrag8 b[4][4];
#pragma unroll
    for (int nt = 0; nt < 4; ++nt)
#pragma unroll
        for (int kt = 0; kt < 4; ++kt)
            b[nt][kt] =
                *(const bfrag8*)(BT + (nt * 16 + m) * 128 + kt * 32 + g * 8);

    float bias[4];
#pragma unroll
    for (int nt = 0; nt < 4; ++nt)
        bias[nt] = b1[nt * 16 + m] + b2[nt * 16 + m];

    // stage A tile: sli = ego+side, pr = ego*side (slot-wise, 16B loads)
#pragma unroll
    for (int it = 0; it < 2; ++it) {
        int idx = it * 256 + tid;     // 0..511
        int n = idx >> 3, c = idx & 7;  // row, 8-slot chunk
        int node = base + n;
        uint4 ev = make_uint4(0, 0, 0, 0), sv = make_uint4(0, 0, 0, 0);
        if (node < N_NODES) {
            ev = ((const uint4*)ego)[(size_t)node * 8 + c];
            sv = ((const uint4*)side_bf)[(size_t)node * 8 + c];
        }
        unsigned evu[4] = {ev.x, ev.y, ev.z, ev.w};
        unsigned svu[4] = {sv.x, sv.y, sv.z, sv.w};
        unsigned qv[4], pq[4];
#pragma unroll
        for (int j = 0; j < 4; ++j) {
            float e0 = bf2f((unsigned short)(evu[j] & 0xffffu));
            float e1 = bf2f((unsigned short)(evu[j] >> 16));
            float s0 = bf2f((unsigned short)(svu[j] & 0xffffu));
            float s1 = bf2f((unsigned short)(svu[j] >> 16));
            qv[j] = f2bf(e0 + s0) | ((unsigned)f2bf(e1 + s1) << 16);
            pq[j] = f2bf(e0 * s0) | ((unsigned)f2bf(e1 * s1) << 16);
        }
        *(uint4*)&A_lds[n][c * 8]      = make_uint4(qv[0], qv[1], qv[2], qv[3]);
        *(uint4*)&A_lds[n][64 + c * 8] = make_uint4(pq[0], pq[1], pq[2], pq[3]);
    }
    __syncthreads();

    bfrag8 a[4];
#pragma unroll
    for (int kt = 0; kt < 4; ++kt)
        a[kt] = *(const bfrag8*)&A_lds[wm * 16 + m][kt * 32 + g * 8];

    vf4 acc[4];
#pragma unroll
    for (int nt = 0; nt < 4; ++nt) acc[nt] = (vf4){0.f, 0.f, 0.f, 0.f};
#pragma unroll
    for (int kt = 0; kt < 4; ++kt)
#pragma unroll
        for (int nt = 0; nt < 4; ++nt)
            acc[nt] = __builtin_amdgcn_mfma_f32_16x16x32_bf16(
                a[kt], b[nt][kt], acc[nt], 0, 0, 0);

    float o[4][4];
    float sq[4] = {0.f, 0.f, 0.f, 0.f};
#pragma unroll
    for (int nt = 0; nt < 4; ++nt)
#pragma unroll
        for (int r = 0; r < 4; ++r) {
            float v = acc[nt][r] + bias[nt];
            v = (v >= 0.f) ? v : 0.01f * v;
            o[nt][r] = v;
            sq[r] += v * v;
        }
#pragma unroll
    for (int r = 0; r < 4; ++r)
#pragma unroll
        for (int off = 1; off < 16; off <<= 1)
            sq[r] += __shfl_xor(sq[r], off, 64);  // reduce over m (same rows)

    // epilogue stores: thread's o[nt][r] = dim nt*16+m = slots 4m+nt
    // -> one 8B bf16 store + one 4B fp8 store per r (contiguous!)
#pragma unroll
    for (int r = 0; r < 4; ++r) {
        int row = base + wm * 16 + g * 4 + r;  // C/D: row=(lane>>4)*4+reg
        if (row < N_NODES) {
            uint2 ob;
            ob.x = (unsigned)f2bf(o[0][r]) | ((unsigned)f2bf(o[1][r]) << 16);
            ob.y = (unsigned)f2bf(o[2][r]) | ((unsigned)f2bf(o[3][r]) << 16);
            ((uint2*)ego)[(size_t)row * 16 + m] = ob;
            int uf = __builtin_amdgcn_cvt_pk_fp8_f32(
                o[0][r] * F8_SCALE, o[1][r] * F8_SCALE, 0, false);
            uf = __builtin_amdgcn_cvt_pk_fp8_f32(
                o[2][r] * F8_SCALE, o[3][r] * F8_SCALE, uf, true);
            ((int*)ego_f8)[(size_t)row * 16 + m] = uf;
            if (m == 0) nrm[row] = fmaxf(sqrtf(sq[r]), 1e-12f);
        }
    }
}

// ---------------- batch accumulation (slot order: reduction-invariant) ---
__global__ __launch_bounds__(256) void batch_kernel(
    const unsigned short* __restrict__ ego_bf, const float* __restrict__ nrm,
    int use_nrm, const int* __restrict__ u, const int* __restrict__ pi,
    const int* __restrict__ ni, float* __restrict__ dot_ui,
    float* __restrict__ dot_uj, float* __restrict__ l2b) {
    const int lane = threadIdx.x & 63;
    int b = (blockIdx.x * blockDim.x + threadIdx.x) >> 6;
    if (b >= BATCH) return;
    int un = u[b];
    int pn = N_USERS + pi[b];
    int nn = N_USERS + ni[b];
    float fu = bf2f(ego_bf[(size_t)un * EMB + lane]);
    float fp = bf2f(ego_bf[(size_t)pn * EMB + lane]);
    float fn_ = bf2f(ego_bf[(size_t)nn * EMB + lane]);
    if (use_nrm) {
        fu /= nrm[un];
        fp /= nrm[pn];
        fn_ /= nrm[nn];
    }
    float dup = fu * fp;
    float dun = fu * fn_;
    float l2  = fu * fu + fp * fp + fn_ * fn_;
#pragma unroll
    for (int off = 32; off; off >>= 1) {
        dup += __shfl_xor(dup, off, 64);
        dun += __shfl_xor(dun, off, 64);
        l2  += __shfl_xor(l2, off, 64);
    }
    if (lane == 0) {
        dot_ui[b] += dup;
        dot_uj[b] += dun;
        l2b[b]    += l2;
    }
}

// ---------------- loss stage 1: parallel softplus + block partials ------
__global__ __launch_bounds__(256) void loss_partial_kernel(
    const float* __restrict__ dot_ui, const float* __restrict__ dot_uj,
    const float* __restrict__ l2b, float* __restrict__ partial) {
    __shared__ float sl[256], s2[256];
    const int t = threadIdx.x;
    const int b = blockIdx.x * 256 + t;  // 64 blocks x 256 = 16384 = BATCH
    float x = dot_ui[b] - dot_uj[b];
    float sp = (x > 0.f) ? log1pf(expf(-x)) : (-x + log1pf(expf(x)));
    sl[t] = sp;
    s2[t] = l2b[b];
    __syncthreads();
    for (int off = 128; off; off >>= 1) {
        if (t < off) {
            sl[t] += sl[t + off];
            s2[t] += s2[t + off];
        }
        __syncthreads();
    }
    if (t == 0) {
        partial[blockIdx.x]      = sl[0];
        partial[64 + blockIdx.x] = s2[0];
    }
}

// ---------------- loss stage 2: one wave reduces 64 partials ------------
__global__ void loss_final_kernel(const float* __restrict__ partial,
                                  float* __restrict__ out) {
    const int t = threadIdx.x;  // 64 threads
    float sp = partial[t];
    float l2 = partial[64 + t];
#pragma unroll
    for (int off = 32; off; off >>= 1) {
        sp += __shfl_down(sp, off, 64);
        l2 += __shfl_down(l2, off, 64);
    }
    if (t == 0)
        out[0] = sp / (float)BATCH + REG * (l2 * 0.5f / (float)BATCH);
}

extern "C" void kernel_launch(void* const* d_in, const int* in_sizes, int n_in,
                              void* d_out, int out_size, void* d_ws,
                              size_t ws_size, hipStream_t stream) {
    const int*   adj_row  = (const int*)d_in[0];
    const int*   adj_col  = (const int*)d_in[1];
    const float* adj_val  = (const float*)d_in[2];
    const float* user_emb = (const float*)d_in[3];
    const float* item_emb = (const float*)d_in[4];
    const float* W1       = (const float*)d_in[5];
    const float* b1       = (const float*)d_in[6];
    const float* W2       = (const float*)d_in[7];
    const float* b2       = (const float*)d_in[8];
    const int*   u        = (const int*)d_in[9];
    const int*   ii       = (const int*)d_in[10];
    const int*   jj       = (const int*)d_in[11];

    char* p = (char*)d_ws;
    auto alloc = [&](size_t bytes) {
        char* q = p;
        p += (bytes + 255) & ~(size_t)255;
        return q;
    };
    unsigned short* ego    = (unsigned short*)alloc((size_t)N_NODES * EMB * 2);
    unsigned char*  ego_f8 = (unsigned char*)alloc((size_t)N_NODES * EMB);
    unsigned short* side_bf= (unsigned short*)alloc((size_t)N_NODES * EMB * 2);
    int2*           sce    = (int2*)alloc((size_t)NNZ * 8);
    int2*           stage  = (int2*)alloc((size_t)NB_BUCKET * BCAP * 8);
    int*            rp     = (int*)alloc((size_t)(N_NODES + 1) * 4);
    int*            bcnt   = (int*)alloc((size_t)NB_BUCKET * 4);
    int*            bbase  = (int*)alloc((size_t)(NB_BUCKET + 1) * 4);
    float*          nrm    = (float*)alloc((size_t)N_NODES * 4);
    float*          dot_ui = (float*)alloc((size_t)BATCH * 4);
    float*          dot_uj = (float*)alloc((size_t)BATCH * 4);
    float*          l2b    = (float*)alloc((size_t)BATCH * 4);
    float*          partial= (float*)alloc(128 * 4);
    unsigned short* BT     = (unsigned short*)alloc((size_t)NLAYERS * 8192 * 2);

    hipMemsetAsync(dot_ui, 0, BATCH * sizeof(float), stream);
    hipMemsetAsync(dot_uj, 0, BATCH * sizeof(float), stream);
    hipMemsetAsync(l2b, 0, BATCH * sizeof(float), stream);
    hipMemsetAsync(bcnt, 0, NB_BUCKET * sizeof(int), stream);

    prep_w_kernel<<<(NLAYERS * 8192 + 255) / 256, 256, 0, stream>>>(W1, W2, BT);

    // ---- build CSR (once; shared by all 3 layers) ----
    binscatter_kernel<<<BIN_NB, 1024, 0, stream>>>(adj_row, adj_col, adj_val,
                                                   bcnt, stage);
    bscan_kernel<<<1, 1024, 0, stream>>>(bcnt, bbase);
    bucket_place_kernel<<<NB_BUCKET, 1024, 0, stream>>>(stage, bcnt, bbase, rp,
                                                        sce);

    init_ego_kernel<<<(N_NODES * 16 + 255) / 256, 256, 0, stream>>>(
        user_emb, item_emb, ego, ego_f8);

    batch_kernel<<<BATCH / 4, 256, 0, stream>>>(ego, nrm, 0, u, ii, jj,
                                                dot_ui, dot_uj, l2b);

    for (int k = 0; k < NLAYERS; ++k) {
        spmm_csr_kernel<<<(N_NODES * 64 + 255) / 256, 256, 0, stream>>>(
            rp, sce, ego_f8, side_bf);
        gemm_dense_kernel<<<NTILES, 256, 0, stream>>>(
            ego, ego_f8, side_bf, BT + (size_t)k * 8192, b1 + (size_t)k * EMB,
            b2 + (size_t)k * EMB, nrm);
        batch_kernel<<<BATCH / 4, 256, 0, stream>>>(ego, nrm, 1, u, ii, jj,
                                                    dot_ui, dot_uj, l2b);
    }

    loss_partial_kernel<<<BATCH / 256, 256, 0, stream>>>(dot_ui, dot_uj, l2b,
                                                         partial);
    loss_final_kernel<<<1, 64, 0, stream>>>(partial, (float*)d_out);
}

// Round 17
// 327.072 us; speedup vs baseline: 4.1635x; 1.1254x over previous
//
#include <hip/hip_runtime.h>

#define N_USERS 100000
#define N_ITEMS 50000
#define N_NODES 150000
#define NNZ     2400000
#define EMB     64
#define NLAYERS 3
#define BATCH   16384
#define REG     1e-5f

#define NTILES ((N_NODES + 63) / 64)  // 2344

#define ROWS_PER_BUCKET 256
#define NB_BUCKET ((N_NODES + ROWS_PER_BUCKET - 1) / ROWS_PER_BUCKET)  // 586
#define BIN_CHUNK 16384
#define BIN_NB ((NNZ + BIN_CHUNK - 1) / BIN_CHUNK)  // 147
#define BCAP 6144   // per-bucket staging capacity: mean 4096, sigma 64

// fp8 mirror scale: keeps values out of the e4m3 denormal zone
#define F8_SCALE 16.0f
#define F8_INV   0.0625f

typedef __attribute__((ext_vector_type(8))) short bfrag8;  // 8 bf16 (4 VGPRs)
typedef __attribute__((ext_vector_type(4))) float vf4;     // 4 f32 acc
typedef __attribute__((ext_vector_type(2))) float f32x2;

// Slot layout: slot p = 4*q + j  <->  dim 16*j + q  (q in [0,16), j in [0,4))
// ego_bf / ego_f8 / side_bf stored in slot order; BT's k-axis permuted
// identically in prep_w => MFMA dot unchanged. batch/nrm are full-row
// reductions (permutation invariant).

__device__ inline unsigned short f2bf(float x) {  // f32 -> bf16 RTN-even
    unsigned int u = __builtin_bit_cast(unsigned int, x);
    return (unsigned short)((u + 0x7fffu + ((u >> 16) & 1u)) >> 16);
}
__device__ inline float bf2f(unsigned short h) {
    unsigned int u = ((unsigned int)h) << 16;
    return __builtin_bit_cast(float, u);
}

// ---------------- init: ego_bf + ego_f8 (slot layout) ----------------
__global__ __launch_bounds__(256) void init_ego_kernel(
    const float* __restrict__ ue, const float* __restrict__ ie,
    unsigned short* __restrict__ ego_bf, unsigned char* __restrict__ ego_f8) {
    int idx = blockIdx.x * 256 + threadIdx.x;
    if (idx >= N_NODES * 16) return;
    int row = idx >> 4, q = idx & 15;
    const float* src = (row < N_USERS)
                           ? ue + (size_t)row * 64
                           : ie + (size_t)(row - N_USERS) * 64;
    float v0 = src[q], v1 = src[16 + q], v2 = src[32 + q], v3 = src[48 + q];
    uint2 o;
    o.x = (unsigned)f2bf(v0) | ((unsigned)f2bf(v1) << 16);
    o.y = (unsigned)f2bf(v2) | ((unsigned)f2bf(v3) << 16);
    ((uint2*)ego_bf)[(size_t)row * 16 + q] = o;
    int u = __builtin_amdgcn_cvt_pk_fp8_f32(v0 * F8_SCALE, v1 * F8_SCALE, 0,
                                            false);
    u = __builtin_amdgcn_cvt_pk_fp8_f32(v2 * F8_SCALE, v3 * F8_SCALE, u, true);
    ((int*)ego_f8)[(size_t)row * 16 + q] = u;
}

// ---------------- prep: BT[l][j][k] = bf16(W[dim(k)][j]), k slot-permuted
__global__ __launch_bounds__(256) void prep_w_kernel(
    const float* __restrict__ W1, const float* __restrict__ W2,
    unsigned short* __restrict__ BT) {
    int idx = blockIdx.x * blockDim.x + threadIdx.x;
    if (idx >= NLAYERS * 64 * 128) return;
    int l = idx / 8192;
    int rem = idx - l * 8192;
    int j = rem >> 7;        // output dim (row of BT)
    int k = rem & 127;       // concat-K slot
    int p = k & 63;
    int d = ((p & 3) << 4) | (p >> 2);  // true dim of slot p
    float w = (k < 64) ? W1[l * 4096 + d * 64 + j]
                       : W2[l * 4096 + d * 64 + j];
    BT[idx] = f2bf(w);
}

// ---------------- pass A: bucket-binned scatter (fixed-cap regions) -----
// 147 blocks x 16K edges: 4x fewer bcnt atomic RMWs per counter, and
// ~224B staging fragments (vs 56B) => write amp ~1.3x (was 2.9x).
__global__ __launch_bounds__(1024) void binscatter_kernel(
    const int* __restrict__ row, const int* __restrict__ col,
    const float* __restrict__ val, int* __restrict__ bcnt,
    int2* __restrict__ stage) {
    __shared__ int hist[NB_BUCKET];
    __shared__ int wbase[NB_BUCKET];
    const int t = threadIdx.x;
    const int s = blockIdx.x * BIN_CHUNK;
    const int e = min(s + BIN_CHUNK, NNZ);

    for (int b = t; b < NB_BUCKET; b += 1024) hist[b] = 0;
    __syncthreads();
    for (int i = s + t; i < e; i += 1024)
        atomicAdd(&hist[row[i] >> 8], 1);
    __syncthreads();
    for (int b = t; b < NB_BUCKET; b += 1024) {
        int c = hist[b];
        wbase[b] = c ? atomicAdd(&bcnt[b], c) : 0;
        hist[b] = 0;  // reuse as local cursor
    }
    __syncthreads();
    for (int i = s + t; i < e; i += 1024) {
        int r = row[i];
        int b = r >> 8;
        int off = atomicAdd(&hist[b], 1);
        stage[(size_t)b * BCAP + wbase[b] + off] =
            make_int2(col[i] | ((r & 255) << 18),
                      __builtin_bit_cast(int, val[i]));
    }
}

// ---------------- bucket scan: CSR bases from measured counts -----------
__global__ __launch_bounds__(1024) void bscan_kernel(
    const int* __restrict__ bcnt, int* __restrict__ bbase) {
    __shared__ int sc[1024];
    const int t = threadIdx.x;
    int v = (t < NB_BUCKET) ? bcnt[t] : 0;
    sc[t] = v;
    __syncthreads();
    int x = v;
    for (int off = 1; off < 1024; off <<= 1) {
        int y = (t >= off) ? sc[t - off] : 0;
        __syncthreads();
        x += y;
        sc[t] = x;
        __syncthreads();
    }
    if (t < NB_BUCKET) bbase[t] = x - v;  // exclusive
    if (t == 0) bbase[NB_BUCKET] = NNZ;
}

// ---------------- pass B: row-count + scan + CSR placement --------------
__global__ __launch_bounds__(1024) void bucket_place_kernel(
    const int2* __restrict__ stage, const int* __restrict__ bcnt,
    const int* __restrict__ bbase, int* __restrict__ rp,
    int2* __restrict__ sce) {
    __shared__ int cnt[ROWS_PER_BUCKET];
    __shared__ int sc[ROWS_PER_BUCKET];
    __shared__ int cur[ROWS_PER_BUCKET];
    const int b = blockIdx.x;
    const int t = threadIdx.x;
    const int row0 = b * ROWS_PER_BUCKET;
    const size_t S0 = (size_t)b * BCAP;
    const int ne = bcnt[b];
    const int B0 = bbase[b];
    if (t < 256) cnt[t] = 0;
    __syncthreads();
    for (int i = t; i < ne; i += 1024)
        atomicAdd(&cnt[(stage[S0 + i].x >> 18) & 255], 1);
    __syncthreads();
    int v = 0, x = 0;
    if (t < 256) { v = cnt[t]; x = v; sc[t] = v; }
    __syncthreads();
    for (int off = 1; off < 256; off <<= 1) {
        int y = (t < 256 && t >= off) ? sc[t - off] : 0;
        __syncthreads();
        if (t < 256) { x += y; sc[t] = x; }
        __syncthreads();
    }
    if (t < 256) {
        int excl = x - v;
        int row = row0 + t;
        if (row <= N_NODES) rp[row] = B0 + excl;  // row==N_NODES -> NNZ
        cur[t] = B0 + excl;
    }
    __syncthreads();
    for (int i = t; i < ne; i += 1024) {
        int2 pk = stage[S0 + i];
        int rl = (pk.x >> 18) & 255;
        int pos = atomicAdd(&cur[rl], 1);
        sce[pos] = make_int2(pk.x & 0x3FFFF, pk.y);
    }
}

// ---------------- CSR SpMM: 2 rows/wave, quarter-wave fp8 gathers -------
// Wave handles rows 2w, 2w+1. Phase-interleaved: issue BOTH rows' sce
// loads, then both rows' gathers, then both FMA blocks => 32 edges in
// flight per dependency chain (was 16). Tail = one predicated 16-batch
// per row (clamped idx, zeroed weight). All guards wave-uniform.
__global__ __launch_bounds__(256) void spmm_csr_kernel(
    const int* __restrict__ rp, const int2* __restrict__ sce,
    const unsigned char* __restrict__ ego_f8,
    unsigned short* __restrict__ side_bf) {
    const int lane = threadIdx.x & 63;
    const int q    = lane >> 4;   // which edge of the 4-group
    const int ql   = lane & 15;   // slot-quad index
    int w = (blockIdx.x * blockDim.x + threadIdx.x) >> 6;
    int r0 = 2 * w;
    if (r0 >= N_NODES) return;
    int r1 = r0 + 1;
    const bool has1 = (r1 < N_NODES);
    const int* egoF = (const int*)ego_f8;  // row stride 16 ints
    int s0 = rp[r0];
    int e0 = rp[r0 + 1];
    int s1 = e0;                          // rows contiguous in CSR
    int e1 = has1 ? rp[r0 + 2] : e0;
    float A0 = 0.f, A1 = 0.f, A2 = 0.f, A3 = 0.f;
    float B0 = 0.f, B1 = 0.f, B2 = 0.f, B3 = 0.f;

#define F8A(gi, wi)                                                          \
    {                                                                        \
        f32x2 lo_ = __builtin_amdgcn_cvt_pk_f32_fp8(gi, false);              \
        f32x2 hi_ = __builtin_amdgcn_cvt_pk_f32_fp8(gi, true);               \
        A0 = fmaf(wi, lo_.x, A0);                                            \
        A1 = fmaf(wi, lo_.y, A1);                                            \
        A2 = fmaf(wi, hi_.x, A2);                                            \
        A3 = fmaf(wi, hi_.y, A3);                                            \
    }
#define F8B(gi, wi)                                                          \
    {                                                                        \
        f32x2 lo_ = __builtin_amdgcn_cvt_pk_f32_fp8(gi, false);              \
        f32x2 hi_ = __builtin_amdgcn_cvt_pk_f32_fp8(gi, true);               \
        B0 = fmaf(wi, lo_.x, B0);                                            \
        B1 = fmaf(wi, lo_.y, B1);                                            \
        B2 = fmaf(wi, hi_.x, B2);                                            \
        B3 = fmaf(wi, hi_.y, B3);                                            \
    }

    int k0 = s0, k1 = s1;
    // ---- main: full 16-edge batches, both rows interleaved ----
    while (k0 + 15 < e0 || k1 + 15 < e1) {
        bool d0 = (k0 + 15 < e0), d1 = (k1 + 15 < e1);
        int2 cA0, cA1, cA2, cA3, cB0, cB1, cB2, cB3;
        int gA0 = 0, gA1 = 0, gA2 = 0, gA3 = 0;
        int gB0 = 0, gB1 = 0, gB2 = 0, gB3 = 0;
        if (d0) {
            cA0 = sce[k0 + q];      cA1 = sce[k0 + 4 + q];
            cA2 = sce[k0 + 8 + q];  cA3 = sce[k0 + 12 + q];
        }
        if (d1) {
            cB0 = sce[k1 + q];      cB1 = sce[k1 + 4 + q];
            cB2 = sce[k1 + 8 + q];  cB3 = sce[k1 + 12 + q];
        }
        if (d0) {
            gA0 = egoF[(size_t)cA0.x * 16 + ql];
            gA1 = egoF[(size_t)cA1.x * 16 + ql];
            gA2 = egoF[(size_t)cA2.x * 16 + ql];
            gA3 = egoF[(size_t)cA3.x * 16 + ql];
        }
        if (d1) {
            gB0 = egoF[(size_t)cB0.x * 16 + ql];
            gB1 = egoF[(size_t)cB1.x * 16 + ql];
            gB2 = egoF[(size_t)cB2.x * 16 + ql];
            gB3 = egoF[(size_t)cB3.x * 16 + ql];
        }
        if (d0) {
            F8A(gA0, __builtin_bit_cast(float, cA0.y))
            F8A(gA1, __builtin_bit_cast(float, cA1.y))
            F8A(gA2, __builtin_bit_cast(float, cA2.y))
            F8A(gA3, __builtin_bit_cast(float, cA3.y))
            k0 += 16;
        }
        if (d1) {
            F8B(gB0, __builtin_bit_cast(float, cB0.y))
            F8B(gB1, __builtin_bit_cast(float, cB1.y))
            F8B(gB2, __builtin_bit_cast(float, cB2.y))
            F8B(gB3, __builtin_bit_cast(float, cB3.y))
            k1 += 16;
        }
    }
    // ---- tail: one predicated 16-batch per row, interleaved ----
    {
        bool t0 = (k0 < e0), t1 = (k1 < e1);
        int2 cA0, cA1, cA2, cA3, cB0, cB1, cB2, cB3;
        int gA0 = 0, gA1 = 0, gA2 = 0, gA3 = 0;
        int gB0 = 0, gB1 = 0, gB2 = 0, gB3 = 0;
        if (t0) {
            int la = e0 - 1;
            cA0 = sce[min(k0 + q, la)];      cA1 = sce[min(k0 + 4 + q, la)];
            cA2 = sce[min(k0 + 8 + q, la)];  cA3 = sce[min(k0 + 12 + q, la)];
        }
        if (t1) {
            int lb = e1 - 1;
            cB0 = sce[min(k1 + q, lb)];      cB1 = sce[min(k1 + 4 + q, lb)];
            cB2 = sce[min(k1 + 8 + q, lb)];  cB3 = sce[min(k1 + 12 + q, lb)];
        }
        if (t0) {
            gA0 = egoF[(size_t)cA0.x * 16 + ql];
            gA1 = egoF[(size_t)cA1.x * 16 + ql];
            gA2 = egoF[(size_t)cA2.x * 16 + ql];
            gA3 = egoF[(size_t)cA3.x * 16 + ql];
        }
        if (t1) {
            gB0 = egoF[(size_t)cB0.x * 16 + ql];
            gB1 = egoF[(size_t)cB1.x * 16 + ql];
            gB2 = egoF[(size_t)cB2.x * 16 + ql];
            gB3 = egoF[(size_t)cB3.x * 16 + ql];
        }
        if (t0) {
            float w0 = (k0 + q      < e0) ? __builtin_bit_cast(float, cA0.y) : 0.f;
            float w1 = (k0 + 4 + q  < e0) ? __builtin_bit_cast(float, cA1.y) : 0.f;
            float w2 = (k0 + 8 + q  < e0) ? __builtin_bit_cast(float, cA2.y) : 0.f;
            float w3 = (k0 + 12 + q < e0) ? __builtin_bit_cast(float, cA3.y) : 0.f;
            F8A(gA0, w0) F8A(gA1, w1) F8A(gA2, w2) F8A(gA3, w3)
        }
        if (t1) {
            float w0 = (k1 + q      < e1) ? __builtin_bit_cast(float, cB0.y) : 0.f;
            float w1 = (k1 + 4 + q  < e1) ? __builtin_bit_cast(float, cB1.y) : 0.f;
            float w2 = (k1 + 8 + q  < e1) ? __builtin_bit_cast(float, cB2.y) : 0.f;
            float w3 = (k1 + 12 + q < e1) ? __builtin_bit_cast(float, cB3.y) : 0.f;
            F8B(gB0, w0) F8B(gB1, w1) F8B(gB2, w2) F8B(gB3, w3)
        }
    }
#undef F8A
#undef F8B
    // combine the 4 quarters (quarter bits are lane bits 4 and 5)
    A0 += __shfl_xor(A0, 32, 64); A0 += __shfl_xor(A0, 16, 64);
    A1 += __shfl_xor(A1, 32, 64); A1 += __shfl_xor(A1, 16, 64);
    A2 += __shfl_xor(A2, 32, 64); A2 += __shfl_xor(A2, 16, 64);
    A3 += __shfl_xor(A3, 32, 64); A3 += __shfl_xor(A3, 16, 64);
    B0 += __shfl_xor(B0, 32, 64); B0 += __shfl_xor(B0, 16, 64);
    B1 += __shfl_xor(B1, 32, 64); B1 += __shfl_xor(B1, 16, 64);
    B2 += __shfl_xor(B2, 32, 64); B2 += __shfl_xor(B2, 16, 64);
    B3 += __shfl_xor(B3, 32, 64); B3 += __shfl_xor(B3, 16, 64);
    if (q == 0) {
        uint2 oA;
        oA.x = (unsigned)f2bf(A0 * F8_INV) | ((unsigned)f2bf(A1 * F8_INV) << 16);
        oA.y = (unsigned)f2bf(A2 * F8_INV) | ((unsigned)f2bf(A3 * F8_INV) << 16);
        ((uint2*)side_bf)[(size_t)r0 * 16 + ql] = oA;
        if (has1) {
            uint2 oB;
            oB.x = (unsigned)f2bf(B0 * F8_INV) |
                   ((unsigned)f2bf(B1 * F8_INV) << 16);
            oB.y = (unsigned)f2bf(B2 * F8_INV) |
                   ((unsigned)f2bf(B3 * F8_INV) << 16);
            ((uint2*)side_bf)[(size_t)r1 * 16 + ql] = oB;
        }
    }
}

// ---------------- dense via MFMA bf16 (slot layout everywhere) ----------
__global__ __launch_bounds__(256) void gemm_dense_kernel(
    unsigned short* __restrict__ ego,            // bf16 in/out, slot order
    unsigned char* __restrict__ ego_f8,          // fp8 mirror out
    const unsigned short* __restrict__ side_bf,  // slot order
    const unsigned short* __restrict__ BT, const float* __restrict__ b1,
    const float* __restrict__ b2, float* __restrict__ nrm) {
    __shared__ unsigned short A_lds[64][136];  // 272B row stride, 16B aligned
    const int tid  = threadIdx.x;
    const int lane = tid & 63, wm = tid >> 6;
    const int m = lane & 15, g = lane >> 4;
    const int base = blockIdx.x * 64;

    bfrag8 b[4][4];
#pragma unroll
    for (int nt = 0; nt < 4; ++nt)
#pragma unroll
        for (int kt = 0; kt < 4; ++kt)
            b[nt][kt] =
                *(const bfrag8*)(BT + (nt * 16 + m) * 128 + kt * 32 + g * 8);

    float bias[4];
#pragma unroll
    for (int nt = 0; nt < 4; ++nt)
        bias[nt] = b1[nt * 16 + m] + b2[nt * 16 + m];

    // stage A tile: sli = ego+side, pr = ego*side (slot-wise, 16B loads)
#pragma unroll
    for (int it = 0; it < 2; ++it) {
        int idx = it * 256 + tid;     // 0..511
        int n = idx >> 3, c = idx & 7;  // row, 8-slot chunk
        int node = base + n;
        uint4 ev = make_uint4(0, 0, 0, 0), sv = make_uint4(0, 0, 0, 0);
        if (node < N_NODES) {
            ev = ((const uint4*)ego)[(size_t)node * 8 + c];
            sv = ((const uint4*)side_bf)[(size_t)node * 8 + c];
        }
        unsigned evu[4] = {ev.x, ev.y, ev.z, ev.w};
        unsigned svu[4] = {sv.x, sv.y, sv.z, sv.w};
        unsigned qv[4], pq[4];
#pragma unroll
        for (int j = 0; j < 4; ++j) {
            float e0 = bf2f((unsigned short)(evu[j] & 0xffffu));
            float e1 = bf2f((unsigned short)(evu[j] >> 16));
            float s0 = bf2f((unsigned short)(svu[j] & 0xffffu));
            float s1 = bf2f((unsigned short)(svu[j] >> 16));
            qv[j] = f2bf(e0 + s0) | ((unsigned)f2bf(e1 + s1) << 16);
            pq[j] = f2bf(e0 * s0) | ((unsigned)f2bf(e1 * s1) << 16);
        }
        *(uint4*)&A_lds[n][c * 8]      = make_uint4(qv[0], qv[1], qv[2], qv[3]);
        *(uint4*)&A_lds[n][64 + c * 8] = make_uint4(pq[0], pq[1], pq[2], pq[3]);
    }
    __syncthreads();

    bfrag8 a[4];
#pragma unroll
    for (int kt = 0; kt < 4; ++kt)
        a[kt] = *(const bfrag8*)&A_lds[wm * 16 + m][kt * 32 + g * 8];

    vf4 acc[4];
#pragma unroll
    for (int nt = 0; nt < 4; ++nt) acc[nt] = (vf4){0.f, 0.f, 0.f, 0.f};
#pragma unroll
    for (int kt = 0; kt < 4; ++kt)
#pragma unroll
        for (int nt = 0; nt < 4; ++nt)
            acc[nt] = __builtin_amdgcn_mfma_f32_16x16x32_bf16(
                a[kt], b[nt][kt], acc[nt], 0, 0, 0);

    float o[4][4];
    float sq[4] = {0.f, 0.f, 0.f, 0.f};
#pragma unroll
    for (int nt = 0; nt < 4; ++nt)
#pragma unroll
        for (int r = 0; r < 4; ++r) {
            float v = acc[nt][r] + bias[nt];
            v = (v >= 0.f) ? v : 0.01f * v;
            o[nt][r] = v;
            sq[r] += v * v;
        }
#pragma unroll
    for (int r = 0; r < 4; ++r)
#pragma unroll
        for (int off = 1; off < 16; off <<= 1)
            sq[r] += __shfl_xor(sq[r], off, 64);  // reduce over m (same rows)

    // epilogue: thread's o[nt][r] = dim nt*16+m = slots 4m+nt -> 8B+4B stores
#pragma unroll
    for (int r = 0; r < 4; ++r) {
        int row = base + wm * 16 + g * 4 + r;  // C/D: row=(lane>>4)*4+reg
        if (row < N_NODES) {
            uint2 ob;
            ob.x = (unsigned)f2bf(o[0][r]) | ((unsigned)f2bf(o[1][r]) << 16);
            ob.y = (unsigned)f2bf(o[2][r]) | ((unsigned)f2bf(o[3][r]) << 16);
            ((uint2*)ego)[(size_t)row * 16 + m] = ob;
            int uf = __builtin_amdgcn_cvt_pk_fp8_f32(
                o[0][r] * F8_SCALE, o[1][r] * F8_SCALE, 0, false);
            uf = __builtin_amdgcn_cvt_pk_fp8_f32(
                o[2][r] * F8_SCALE, o[3][r] * F8_SCALE, uf, true);
            ((int*)ego_f8)[(size_t)row * 16 + m] = uf;
            if (m == 0) nrm[row] = fmaxf(sqrtf(sq[r]), 1e-12f);
        }
    }
}

// ---------------- batch accumulation (slot order: reduction-invariant) ---
__global__ __launch_bounds__(256) void batch_kernel(
    const unsigned short* __restrict__ ego_bf, const float* __restrict__ nrm,
    int use_nrm, const int* __restrict__ u, const int* __restrict__ pi,
    const int* __restrict__ ni, float* __restrict__ dot_ui,
    float* __restrict__ dot_uj, float* __restrict__ l2b) {
    const int lane = threadIdx.x & 63;
    int b = (blockIdx.x * blockDim.x + threadIdx.x) >> 6;
    if (b >= BATCH) return;
    int un = u[b];
    int pn = N_USERS + pi[b];
    int nn = N_USERS + ni[b];
    float fu = bf2f(ego_bf[(size_t)un * EMB + lane]);
    float fp = bf2f(ego_bf[(size_t)pn * EMB + lane]);
    float fn_ = bf2f(ego_bf[(size_t)nn * EMB + lane]);
    if (use_nrm) {
        fu /= nrm[un];
        fp /= nrm[pn];
        fn_ /= nrm[nn];
    }
    float dup = fu * fp;
    float dun = fu * fn_;
    float l2  = fu * fu + fp * fp + fn_ * fn_;
#pragma unroll
    for (int off = 32; off; off >>= 1) {
        dup += __shfl_xor(dup, off, 64);
        dun += __shfl_xor(dun, off, 64);
        l2  += __shfl_xor(l2, off, 64);
    }
    if (lane == 0) {
        dot_ui[b] += dup;
        dot_uj[b] += dun;
        l2b[b]    += l2;
    }
}

// ---------------- loss stage 1: parallel softplus + block partials ------
__global__ __launch_bounds__(256) void loss_partial_kernel(
    const float* __restrict__ dot_ui, const float* __restrict__ dot_uj,
    const float* __restrict__ l2b, float* __restrict__ partial) {
    __shared__ float sl[256], s2[256];
    const int t = threadIdx.x;
    const int b = blockIdx.x * 256 + t;  // 64 blocks x 256 = 16384 = BATCH
    float x = dot_ui[b] - dot_uj[b];
    float sp = (x > 0.f) ? log1pf(expf(-x)) : (-x + log1pf(expf(x)));
    sl[t] = sp;
    s2[t] = l2b[b];
    __syncthreads();
    for (int off = 128; off; off >>= 1) {
        if (t < off) {
            sl[t] += sl[t + off];
            s2[t] += s2[t + off];
        }
        __syncthreads();
    }
    if (t == 0) {
        partial[blockIdx.x]      = sl[0];
        partial[64 + blockIdx.x] = s2[0];
    }
}

// ---------------- loss stage 2: one wave reduces 64 partials ------------
__global__ void loss_final_kernel(const float* __restrict__ partial,
                                  float* __restrict__ out) {
    const int t = threadIdx.x;  // 64 threads
    float sp = partial[t];
    float l2 = partial[64 + t];
#pragma unroll
    for (int off = 32; off; off >>= 1) {
        sp += __shfl_down(sp, off, 64);
        l2 += __shfl_down(l2, off, 64);
    }
    if (t == 0)
        out[0] = sp / (float)BATCH + REG * (l2 * 0.5f / (float)BATCH);
}

extern "C" void kernel_launch(void* const* d_in, const int* in_sizes, int n_in,
                              void* d_out, int out_size, void* d_ws,
                              size_t ws_size, hipStream_t stream) {
    const int*   adj_row  = (const int*)d_in[0];
    const int*   adj_col  = (const int*)d_in[1];
    const float* adj_val  = (const float*)d_in[2];
    const float* user_emb = (const float*)d_in[3];
    const float* item_emb = (const float*)d_in[4];
    const float* W1       = (const float*)d_in[5];
    const float* b1       = (const float*)d_in[6];
    const float* W2       = (const float*)d_in[7];
    const float* b2       = (const float*)d_in[8];
    const int*   u        = (const int*)d_in[9];
    const int*   ii       = (const int*)d_in[10];
    const int*   jj       = (const int*)d_in[11];

    char* p = (char*)d_ws;
    auto alloc = [&](size_t bytes) {
        char* q = p;
        p += (bytes + 255) & ~(size_t)255;
        return q;
    };
    unsigned short* ego    = (unsigned short*)alloc((size_t)N_NODES * EMB * 2);
    unsigned char*  ego_f8 = (unsigned char*)alloc((size_t)N_NODES * EMB);
    unsigned short* side_bf= (unsigned short*)alloc((size_t)N_NODES * EMB * 2);
    int2*           sce    = (int2*)alloc((size_t)NNZ * 8);
    int2*           stage  = (int2*)alloc((size_t)NB_BUCKET * BCAP * 8);
    int*            rp     = (int*)alloc((size_t)(N_NODES + 1) * 4);
    int*            bcnt   = (int*)alloc((size_t)NB_BUCKET * 4);
    int*            bbase  = (int*)alloc((size_t)(NB_BUCKET + 1) * 4);
    float*          nrm    = (float*)alloc((size_t)N_NODES * 4);
    float*          dot_ui = (float*)alloc((size_t)BATCH * 4);
    float*          dot_uj = (float*)alloc((size_t)BATCH * 4);
    float*          l2b    = (float*)alloc((size_t)BATCH * 4);
    float*          partial= (float*)alloc(128 * 4);
    unsigned short* BT     = (unsigned short*)alloc((size_t)NLAYERS * 8192 * 2);

    hipMemsetAsync(dot_ui, 0, BATCH * sizeof(float), stream);
    hipMemsetAsync(dot_uj, 0, BATCH * sizeof(float), stream);
    hipMemsetAsync(l2b, 0, BATCH * sizeof(float), stream);
    hipMemsetAsync(bcnt, 0, NB_BUCKET * sizeof(int), stream);

    prep_w_kernel<<<(NLAYERS * 8192 + 255) / 256, 256, 0, stream>>>(W1, W2, BT);

    // ---- build CSR (once; shared by all 3 layers) ----
    binscatter_kernel<<<BIN_NB, 1024, 0, stream>>>(adj_row, adj_col, adj_val,
                                                   bcnt, stage);
    bscan_kernel<<<1, 1024, 0, stream>>>(bcnt, bbase);
    bucket_place_kernel<<<NB_BUCKET, 1024, 0, stream>>>(stage, bcnt, bbase, rp,
                                                        sce);

    init_ego_kernel<<<(N_NODES * 16 + 255) / 256, 256, 0, stream>>>(
        user_emb, item_emb, ego, ego_f8);

    batch_kernel<<<BATCH / 4, 256, 0, stream>>>(ego, nrm, 0, u, ii, jj,
                                                dot_ui, dot_uj, l2b);

    const int spmm_blocks = ((N_NODES + 1) / 2 * 64 + 255) / 256;  // 18750
    for (int k = 0; k < NLAYERS; ++k) {
        spmm_csr_kernel<<<spmm_blocks, 256, 0, stream>>>(rp, sce, ego_f8,
                                                         side_bf);
        gemm_dense_kernel<<<NTILES, 256, 0, stream>>>(
            ego, ego_f8, side_bf, BT + (size_t)k * 8192, b1 + (size_t)k * EMB,
            b2 + (size_t)k * EMB, nrm);
        batch_kernel<<<BATCH / 4, 256, 0, stream>>>(ego, nrm, 1, u, ii, jj,
                                                    dot_ui, dot_uj, l2b);
    }

    loss_partial_kernel<<<BATCH / 256, 256, 0, stream>>>(dot_ui, dot_uj, l2b,
                                                         partial);
    loss_final_kernel<<<1, 64, 0, stream>>>(partial, (float*)d_out);
}